// Round 15
// baseline (204.590 us; speedup 1.0000x reference)
//
#include <hip/hip_runtime.h>
#include <hip/hip_bf16.h>
#include <math.h>

// Problem constants
#define NH   64     // b*H heads
#define DKC  64     // dim per head
#define MM   4096   // x*y
#define CC   256    // img channels
#define RRN  127    // 2L-1

typedef __hip_bfloat16 bf16;
__device__ __forceinline__ float b2f(bf16 x) { return __bfloat162float(x); }
__device__ __forceinline__ bf16 f2b(float x) { return __float2bfloat16(x); }
__device__ __forceinline__ unsigned short bbits(float x) { bf16 h = f2b(x); return *(unsigned short*)&h; }
__device__ __forceinline__ float fbits(unsigned short u) { bf16 h = *(bf16*)&u; return b2f(h); }

typedef short bf16x8 __attribute__((ext_vector_type(8)));
typedef float f32x4 __attribute__((ext_vector_type(4)));
typedef unsigned short u16;
typedef u16 u16x4 __attribute__((ext_vector_type(4)));
typedef u16 u16x8 __attribute__((ext_vector_type(8)));

#define AS1 __attribute__((address_space(1)))
#define AS3 __attribute__((address_space(3)))
#define GLOAD16(gp, lp) __builtin_amdgcn_global_load_lds((const AS1 void*)(gp), (AS3 void*)(lp), 16, 0, 0)

// swizzled source elem offset for staging (involution partner of FRSWZ)
__device__ __forceinline__ int swzsrc(int lane) { return 8 * ((lane & 7) ^ (lane >> 3)); }
// fragment-read elem index within a 64-elem row, row-swizzled
#define FRSWZ(kelem, row) ((kelem) ^ (((row) & 7) * 8))

// ---------------------------------------------------------------------------
// K0a: merged converts. grid 2112 x 256 covers 540672 slots.
// ---------------------------------------------------------------------------
__global__ __launch_bounds__(256) void k_cvt_all(const float* __restrict__ w_qkv, const float* __restrict__ w_out,
                                                 const float* __restrict__ relc, const float* __restrict__ relr,
                                                 bf16* __restrict__ wb, bf16* __restrict__ wb2,
                                                 bf16* __restrict__ relcb, bf16* __restrict__ relrb) {
  const int i = blockIdx.x * 256 + threadIdx.x;
  if (i < 393216) {
    wb[i] = f2b(w_qkv[i]);
  } else if (i < 524288) {
    int j = i - 393216; wb2[j] = f2b(w_out[j]);
  } else if (i < 532480) {
    int j = i - 524288; relcb[j] = (j < RRN * 64) ? f2b(relc[j]) : f2b(0.f);
  } else {
    int j = i - 532480; if (j < RRN * 64) relrb[j] = f2b(relr[j]);
  }
}

// ---------------------------------------------------------------------------
// K0b: img fp32 [8][256][4096] -> bf16 imgT [8][4096][256], vectorized
// ---------------------------------------------------------------------------
__global__ __launch_bounds__(256) void k_timg(const float* __restrict__ img, bf16* __restrict__ imgT) {
  const int b = blockIdx.z, c0 = blockIdx.y * 64, m0 = blockIdx.x * 64;
  const int tid = threadIdx.x;
  __shared__ short T[64 * 66];
  const float* ib = img + ((size_t)b * CC + c0) * MM + m0;
#pragma unroll
  for (int j = 0; j < 4; ++j) {
    int f4 = j * 256 + tid;          // 0..1023
    int cc = f4 >> 4, mm4 = (f4 & 15) * 4;
    f32x4 v = *(const f32x4*)&ib[(size_t)cc * MM + mm4];
#pragma unroll
    for (int k = 0; k < 4; ++k) T[cc * 66 + mm4 + k] = (short)bbits(v[k]);
  }
  __syncthreads();
  bf16* ob = imgT + ((size_t)b * MM + m0) * CC + c0;
#pragma unroll
  for (int j = 0; j < 4; ++j) {
    int f4 = j * 256 + tid;
    int mm = f4 >> 4, cc4 = (f4 & 15) * 4;
    u16x4 pk;
#pragma unroll
    for (int k = 0; k < 4; ++k) pk[k] = (u16)T[(cc4 + k) * 66 + mm];
    *(u16x4*)&ob[(size_t)mm * CC + cc4] = pk;
  }
}

// ---------------------------------------------------------------------------
// K1: MFMA qkv GEMM (128x128 tile, BK=64, 4 waves). Double-buffered staging
// (1 barrier/iter, stage overlaps MFMA), XCD-swizzled blocks, LDS epilogue.
// ---------------------------------------------------------------------------
__global__ __launch_bounds__(256) void k_qkv(const bf16* __restrict__ wb, const bf16* __restrict__ imgT,
                                             bf16* __restrict__ qT, bf16* __restrict__ kk, bf16* __restrict__ v) {
  int flat = blockIdx.x + (blockIdx.y << 5) + blockIdx.z * 384;
  flat = ((flat & 7) * 384) + (flat >> 3);       // bijective XCD swizzle (3072 % 8 == 0)
  const int bI = flat / 384;
  const int r2 = flat - bI * 384;
  const int o0 = (r2 >> 5) * 128;
  const int m0 = (r2 & 31) * 128;
  const int tid = threadIdx.x;
  const int lane = tid & 63, wid = tid >> 6;
  const int fr = lane & 15;
  const int fq = lane >> 4;
  const int wm = (wid >> 1) * 64, wn = (wid & 1) * 64;

  __shared__ __align__(16) short smem[32768];  // A[2][8192] | B[2][8192]; epilogue Cs[128][136]

  const bf16* iB = imgT + (size_t)bI * MM * CC;

  f32x4 acc[4][4];
#pragma unroll
  for (int mi = 0; mi < 4; ++mi)
#pragma unroll
    for (int ni = 0; ni < 4; ++ni) acc[mi][ni] = (f32x4){0.f, 0.f, 0.f, 0.f};

  const int srow = lane >> 3;
  const int skc = swzsrc(lane);

  // prologue: stage kt=0 into buf 0
#pragma unroll
  for (int cc = 0; cc < 4; ++cc) {
    const int c = wid * 4 + cc;
    const int r = c * 8 + srow;
    GLOAD16(wb + (size_t)(o0 + r) * CC + skc, &smem[c * 512]);
    GLOAD16(iB + (size_t)(m0 + r) * CC + skc, &smem[16384 + c * 512]);
  }
  __syncthreads();

#pragma unroll
  for (int kt = 0; kt < 4; ++kt) {
    const int buf = (kt & 1) * 8192;
    if (kt < 3) {
      const int k1 = (kt + 1) * 64;
      const int nbuf = ((kt + 1) & 1) * 8192;
#pragma unroll
      for (int cc = 0; cc < 4; ++cc) {
        const int c = wid * 4 + cc;
        const int r = c * 8 + srow;
        GLOAD16(wb + (size_t)(o0 + r) * CC + k1 + skc, &smem[nbuf + c * 512]);
        GLOAD16(iB + (size_t)(m0 + r) * CC + k1 + skc, &smem[16384 + nbuf + c * 512]);
      }
    }
    bf16x8 af[4][2], bfr[4][2];
#pragma unroll
    for (int mi = 0; mi < 4; ++mi)
#pragma unroll
      for (int kkk = 0; kkk < 2; ++kkk)
        af[mi][kkk] = *(const bf16x8*)&smem[buf + (wm + mi * 16 + fr) * 64 + FRSWZ(kkk * 32 + fq * 8, fr)];
#pragma unroll
    for (int ni = 0; ni < 4; ++ni)
#pragma unroll
      for (int kkk = 0; kkk < 2; ++kkk)
        bfr[ni][kkk] = *(const bf16x8*)&smem[16384 + buf + (wn + ni * 16 + fr) * 64 + FRSWZ(kkk * 32 + fq * 8, fr)];
#pragma unroll
    for (int mi = 0; mi < 4; ++mi)
#pragma unroll
      for (int ni = 0; ni < 4; ++ni)
#pragma unroll
        for (int kkk = 0; kkk < 2; ++kkk)
          acc[mi][ni] = __builtin_amdgcn_mfma_f32_16x16x32_bf16(af[mi][kkk], bfr[ni][kkk], acc[mi][ni], 0, 0, 0);
    __syncthreads();
  }

  short* Cs = smem;  // pitch 136 (16B-aligned rows, bank-shifted)
  if (o0 < 512) {
    // q path: store transposed Cs[m][o] so d is contiguous on output
#pragma unroll
    for (int mi = 0; mi < 4; ++mi)
#pragma unroll
      for (int ni = 0; ni < 4; ++ni)
#pragma unroll
        for (int r = 0; r < 4; ++r)
          Cs[(wn + ni * 16 + fr) * 136 + wm + mi * 16 + fq * 4 + r] = (short)bbits(acc[mi][ni][r]);
    __syncthreads();
    const int n0 = bI * 8 + (o0 >> 6);
#pragma unroll
    for (int j = 0; j < 8; ++j) {
      int f2 = tid + j * 256;
      int m = f2 >> 4, nh = (f2 >> 3) & 1, ds = f2 & 7;
      u16x8 pk = *(const u16x8*)&Cs[m * 136 + nh * 64 + ds * 8];
      *(u16x8*)&qT[((size_t)(n0 + nh) * MM + m0 + m) * 64 + ds * 8] = pk;
    }
  } else {
    // k/v path: Cs[o][m], rows contiguous on output
#pragma unroll
    for (int mi = 0; mi < 4; ++mi)
#pragma unroll
      for (int ni = 0; ni < 4; ++ni)
#pragma unroll
        for (int r = 0; r < 4; ++r)
          Cs[(wm + mi * 16 + fq * 4 + r) * 136 + wn + ni * 16 + fr] = (short)bbits(acc[mi][ni][r]);
    __syncthreads();
    bf16* dst = (o0 < 1024) ? kk : v;
    const int obase = (o0 < 1024) ? (o0 - 512) : (o0 - 1024);
#pragma unroll
    for (int j = 0; j < 8; ++j) {
      int f2 = tid + j * 256;
      int row = f2 >> 4, seg = f2 & 15;
      u16x8 pk = *(const u16x8*)&Cs[row * 136 + seg * 8];
      *(u16x8*)&dst[((size_t)bI * 512 + obase + row) * MM + m0 + seg * 8] = pk;
    }
  }
}

// ---------------------------------------------------------------------------
// K2: in-place softmax, row cached in registers: 1 read + 1 write
// ---------------------------------------------------------------------------
__global__ __launch_bounds__(256) void k_softmax(bf16* __restrict__ kk) {
  const size_t row = blockIdx.x;
  bf16* p = kk + row * (size_t)MM;
  const int t = threadIdx.x;
  __shared__ float sred[4];
  float v[16];
  float mx = -1e30f;
#pragma unroll
  for (int j = 0; j < 4; ++j) {
    u16x4 v4 = *(const u16x4*)&p[(j * 256 + t) * 4];
#pragma unroll
    for (int k = 0; k < 4; ++k) { v[j * 4 + k] = fbits(v4[k]); mx = fmaxf(mx, v[j * 4 + k]); }
  }
#pragma unroll
  for (int off = 32; off; off >>= 1) mx = fmaxf(mx, __shfl_down(mx, off));
  if ((t & 63) == 0) sred[t >> 6] = mx;
  __syncthreads();
  mx = fmaxf(fmaxf(sred[0], sred[1]), fmaxf(sred[2], sred[3]));
  __syncthreads();
  float s = 0.f;
#pragma unroll
  for (int i = 0; i < 16; ++i) { v[i] = expf(v[i] - mx); s += v[i]; }
#pragma unroll
  for (int off = 32; off; off >>= 1) s += __shfl_down(s, off);
  if ((t & 63) == 0) sred[t >> 6] = s;
  __syncthreads();
  s = sred[0] + sred[1] + sred[2] + sred[3];
  const float inv = 1.0f / s;
#pragma unroll
  for (int j = 0; j < 4; ++j) {
    u16x4 o;
#pragma unroll
    for (int k = 0; k < 4; ++k) o[k] = bbits(v[j * 4 + k] * inv);
    *(u16x4*)&p[(j * 256 + t) * 4] = o;
  }
}

// ---------------------------------------------------------------------------
// K3a: MFMA ctx: part[ch][n][d][e] = sum_{m in chunk} k[n,d,m]*v[n,e,m]
// ---------------------------------------------------------------------------
__global__ __launch_bounds__(256) void k_ctx2(const bf16* __restrict__ kk, const bf16* __restrict__ v,
                                              float* __restrict__ part) {
  const int ch = blockIdx.x, n = blockIdx.y;
  const int tid = threadIdx.x;
  const int lane = tid & 63, wid = tid >> 6;
  const int fr = lane & 15, fq = lane >> 4;
  const int wr = (wid >> 1) * 32, wc = (wid & 1) * 32;
  __shared__ __align__(16) short Ks[64 * 64];
  __shared__ __align__(16) short Vs[64 * 64];
  const bf16* kp = kk + (size_t)n * DKC * MM;
  const bf16* vp = v + (size_t)n * DKC * MM;
  const int srow = lane >> 3;
  const int skc = swzsrc(lane);

  f32x4 acc[2][2];
#pragma unroll
  for (int mi = 0; mi < 2; ++mi)
#pragma unroll
    for (int ni = 0; ni < 2; ++ni) acc[mi][ni] = (f32x4){0.f, 0.f, 0.f, 0.f};

  for (int t = 0; t < 16; ++t) {
    const int m0 = ch * 1024 + t * 64;
#pragma unroll
    for (int cc = 0; cc < 4; ++cc) {
      const int c = wid * 4 + cc;
      if (c < 8) {
        const int r = c * 8 + srow;
        GLOAD16(kp + (size_t)r * MM + m0 + skc, &Ks[c * 512]);
      } else {
        const int r = (c - 8) * 8 + srow;
        GLOAD16(vp + (size_t)r * MM + m0 + skc, &Vs[(c - 8) * 512]);
      }
    }
    __syncthreads();
    bf16x8 af[2][2], bf[2][2];
#pragma unroll
    for (int mi = 0; mi < 2; ++mi)
#pragma unroll
      for (int kkx = 0; kkx < 2; ++kkx)
        af[mi][kkx] = *(const bf16x8*)&Ks[(wr + mi * 16 + fr) * 64 + FRSWZ(kkx * 32 + fq * 8, fr)];
#pragma unroll
    for (int ni = 0; ni < 2; ++ni)
#pragma unroll
      for (int kkx = 0; kkx < 2; ++kkx)
        bf[ni][kkx] = *(const bf16x8*)&Vs[(wc + ni * 16 + fr) * 64 + FRSWZ(kkx * 32 + fq * 8, fr)];
#pragma unroll
    for (int mi = 0; mi < 2; ++mi)
#pragma unroll
      for (int ni = 0; ni < 2; ++ni)
#pragma unroll
        for (int kkx = 0; kkx < 2; ++kkx)
          acc[mi][ni] = __builtin_amdgcn_mfma_f32_16x16x32_bf16(af[mi][kkx], bf[ni][kkx], acc[mi][ni], 0, 0, 0);
    __syncthreads();
  }
  float* pb = part + ((size_t)ch * NH + n) * 4096;
#pragma unroll
  for (int mi = 0; mi < 2; ++mi)
#pragma unroll
    for (int ni = 0; ni < 2; ++ni)
#pragma unroll
      for (int r = 0; r < 4; ++r)
        pb[(wr + mi * 16 + fq * 4 + r) * 64 + wc + ni * 16 + fr] = acc[mi][ni][r];
}

// K3b: reduce 4 partials + transpose + convert: part -> ctxTb[n][e][d] bf16
__global__ __launch_bounds__(256) void k_ctxred_T(const float* __restrict__ part, bf16* __restrict__ ctxTb) {
  const int n = blockIdx.x;
  const int tid = threadIdx.x;
  __shared__ float T[64 * 67];  // T[d][e]
  const float* pn = part + (size_t)n * 4096;
#pragma unroll
  for (int l = 0; l < 16; ++l) {
    int idx = tid + l * 256;
    int d = idx >> 6, e = idx & 63;
    float s = 0.f;
#pragma unroll
    for (int c = 0; c < 4; ++c) s += pn[(size_t)c * 262144 + idx];
    T[d * 67 + e] = s;
  }
  __syncthreads();
  bf16* ob = ctxTb + (size_t)n * 4096;
#pragma unroll
  for (int l = 0; l < 4; ++l) {
    int q = tid + l * 256;
    int e = q >> 4, d4 = (q & 15) * 4;
    u16x4 pk;
#pragma unroll
    for (int k = 0; k < 4; ++k) pk[k] = bbits(T[(d4 + k) * 67 + e]);
    *(u16x4*)&ob[e * 64 + d4] = pk;
  }
}

// ---------------------------------------------------------------------------
// K5a: MFMA k_sx2: sxT[n][y][x][i] = sum_d relr[i+63-x][d]*qT[n][x*64+y][d]
// ---------------------------------------------------------------------------
__global__ __launch_bounds__(256) void k_sx2(const bf16* __restrict__ relrb, const bf16* __restrict__ qT,
                                             bf16* __restrict__ sxT) {
  int flat = blockIdx.x + (blockIdx.y << 6);
  flat = ((flat & 7) * 512) + (flat >> 3);
  const int x = flat & 63, n = flat >> 6;
  const int tid = threadIdx.x;
  const int lane = tid & 63, wid = tid >> 6;
  const int fr = lane & 15, fq = lane >> 4;
  const int wr = (wid >> 1) * 32, wc = (wid & 1) * 32;  // wr: i, wc: y
  __shared__ __align__(16) short Qt[64 * 64];   // Qt[y][d], swizzled
  const bf16* qrow = qT + ((size_t)n * MM + x * 64) * 64;
  const int srow = lane >> 3, skc = swzsrc(lane);
#pragma unroll
  for (int cc = 0; cc < 2; ++cc) {
    const int c = wid * 2 + cc;          // 0..7
    const int r = c * 8 + srow;          // y row
    GLOAD16(qrow + (size_t)r * 64 + skc, &Qt[c * 512]);
  }
  bf16x8 af[2][2];
#pragma unroll
  for (int mi = 0; mi < 2; ++mi) {
    const int j = wr + mi * 16 + fr + 63 - x;
#pragma unroll
    for (int kk = 0; kk < 2; ++kk)
      af[mi][kk] = *(const bf16x8*)&relrb[(size_t)j * 64 + kk * 32 + fq * 8];
  }
  __syncthreads();
  bf16x8 bq[2][2];
#pragma unroll
  for (int ni = 0; ni < 2; ++ni) {
    const int row = wc + ni * 16 + fr;
#pragma unroll
    for (int kk = 0; kk < 2; ++kk)
      bq[ni][kk] = *(const bf16x8*)&Qt[row * 64 + FRSWZ(kk * 32 + fq * 8, fr)];
  }
  f32x4 acc[2][2];
#pragma unroll
  for (int mi = 0; mi < 2; ++mi)
#pragma unroll
    for (int ni = 0; ni < 2; ++ni) acc[mi][ni] = (f32x4){0.f, 0.f, 0.f, 0.f};
#pragma unroll
  for (int mi = 0; mi < 2; ++mi)
#pragma unroll
    for (int ni = 0; ni < 2; ++ni)
#pragma unroll
      for (int kk = 0; kk < 2; ++kk)
        acc[mi][ni] = __builtin_amdgcn_mfma_f32_16x16x32_bf16(af[mi][kk], bq[ni][kk], acc[mi][ni], 0, 0, 0);
  // D[row=i][col=y] -> sxT[n][y][x][i], 4 consecutive i per store
#pragma unroll
  for (int mi = 0; mi < 2; ++mi)
#pragma unroll
    for (int ni = 0; ni < 2; ++ni) {
      const int yy2 = wc + ni * 16 + fr;
      u16x4 pk;
#pragma unroll
      for (int r = 0; r < 4; ++r) pk[r] = bbits(acc[mi][ni][r]);
      *(u16x4*)&sxT[(((size_t)n * 64 + yy2) * 64 + x) * 64 + wr + mi * 16 + fq * 4] = pk;
    }
}

// ---------------------------------------------------------------------------
// K5v: k_vt — transpose v[n][e][x][y] -> vT[n][y][e][x]
// ---------------------------------------------------------------------------
__global__ __launch_bounds__(256) void k_vt(const bf16* __restrict__ v, bf16* __restrict__ vT) {
  const int eg = blockIdx.x, n = blockIdx.y;
  const int tid = threadIdx.x;
  __shared__ short T[8 * 64 * 66];  // T[e][y][x], pitch 66
  const bf16* vp = v + (size_t)n * DKC * MM + (size_t)eg * 8 * MM;
#pragma unroll
  for (int j = 0; j < 16; ++j) {
    int flat = (j * 256 + tid) * 8;
    int e = flat >> 12, m = flat & 4095;
    int x = m >> 6, y0 = m & 63;
    u16x4 lo = *(const u16x4*)&vp[(size_t)e * MM + m];
    u16x4 hi = *(const u16x4*)&vp[(size_t)e * MM + m + 4];
#pragma unroll
    for (int k = 0; k < 4; ++k) T[(e * 64 + y0 + k) * 66 + x] = (short)lo[k];
#pragma unroll
    for (int k = 0; k < 4; ++k) T[(e * 64 + y0 + 4 + k) * 66 + x] = (short)hi[k];
  }
  __syncthreads();
#pragma unroll
  for (int j = 0; j < 32; ++j) {
    int flat4 = j * 256 + tid;            // 8192 quads
    int x4 = flat4 & 15, e = (flat4 >> 4) & 7, y = flat4 >> 7;
    u16x4 pk;
#pragma unroll
    for (int r = 0; r < 4; ++r) pk[r] = (u16)T[(e * 64 + y) * 66 + x4 * 4 + r];
    *(u16x4*)&vT[(((size_t)n * 64 + y) * 64 + eg * 8 + e) * 64 + x4 * 4] = pk;
  }
}

// ---------------------------------------------------------------------------
// K5b: k_yh2 — MFMA per (n,y): yhT[n][y][x][e] = sum_i vT[n][y][e][i]*sxT[n][y][x][i]
// ---------------------------------------------------------------------------
__global__ __launch_bounds__(256) void k_yh2(const bf16* __restrict__ vT, const bf16* __restrict__ sxT,
                                             bf16* __restrict__ yhT) {
  int flat = blockIdx.x + (blockIdx.y << 6);
  flat = ((flat & 7) * 512) + (flat >> 3);
  const int y = flat & 63, n = flat >> 6;
  const int tid = threadIdx.x;
  const int lane = tid & 63, wid = tid >> 6;
  const int fr = lane & 15, fq = lane >> 4;
  const int wr = (wid >> 1) * 32, wc = (wid & 1) * 32;  // wr: e, wc: x
  __shared__ __align__(16) short Va[64 * 64];
  __shared__ __align__(16) short Sa[64 * 64];
  const size_t rb = ((size_t)n * 64 + y) * 4096;
  const int srow = lane >> 3;
  const int skc = swzsrc(lane);
#pragma unroll
  for (int cc = 0; cc < 2; ++cc) {
    const int c = wid * 2 + cc;
    const int r = c * 8 + srow;
    GLOAD16(vT + rb + (size_t)r * 64 + skc, &Va[c * 512]);
    GLOAD16(sxT + rb + (size_t)r * 64 + skc, &Sa[c * 512]);
  }
  __syncthreads();
  bf16x8 av[2][2], bs[2][2];
#pragma unroll
  for (int mi = 0; mi < 2; ++mi)
#pragma unroll
    for (int kk = 0; kk < 2; ++kk)
      av[mi][kk] = *(const bf16x8*)&Va[(wr + mi * 16 + fr) * 64 + FRSWZ(kk * 32 + fq * 8, fr)];
#pragma unroll
  for (int ni = 0; ni < 2; ++ni)
#pragma unroll
    for (int kk = 0; kk < 2; ++kk)
      bs[ni][kk] = *(const bf16x8*)&Sa[(wc + ni * 16 + fr) * 64 + FRSWZ(kk * 32 + fq * 8, fr)];
  f32x4 acc[2][2];
#pragma unroll
  for (int mi = 0; mi < 2; ++mi)
#pragma unroll
    for (int ni = 0; ni < 2; ++ni) acc[mi][ni] = (f32x4){0.f, 0.f, 0.f, 0.f};
#pragma unroll
  for (int mi = 0; mi < 2; ++mi)
#pragma unroll
    for (int ni = 0; ni < 2; ++ni)
#pragma unroll
      for (int kk = 0; kk < 2; ++kk)
        acc[mi][ni] = __builtin_amdgcn_mfma_f32_16x16x32_bf16(av[mi][kk], bs[ni][kk], acc[mi][ni], 0, 0, 0);
#pragma unroll
  for (int mi = 0; mi < 2; ++mi)
#pragma unroll
    for (int ni = 0; ni < 2; ++ni) {
      const int xo = wc + ni * 16 + fr;
      u16x4 pk;
#pragma unroll
      for (int r = 0; r < 4; ++r) pk[r] = bbits(acc[mi][ni][r]);
      *(u16x4*)&yhT[rb + (size_t)xo * 64 + wr + mi * 16 + fq * 4] = pk;
    }
}

// ---------------------------------------------------------------------------
// K6a: BN partial stats from yhT. grid (8 row-groups, 64 n)
// ---------------------------------------------------------------------------
__global__ __launch_bounds__(256) void k_bnpart2(const bf16* __restrict__ yhT, float* __restrict__ ps,
                                                 float* __restrict__ ps2) {
  const int gg = blockIdx.x, n = blockIdx.y;
  const int t = threadIdx.x;
  const int eq = (t & 15) * 4, rg = t >> 4;
  const bf16* p = yhT + (size_t)n * 262144 + (size_t)gg * 512 * 64;
  float s[4] = {}, s2[4] = {};
  for (int r = rg; r < 512; r += 16) {
    u16x4 v4 = *(const u16x4*)&p[(size_t)r * 64 + eq];
#pragma unroll
    for (int k = 0; k < 4; ++k) { float x = fbits(v4[k]); s[k] += x; s2[k] += x * x; }
  }
  __shared__ float ls[16][64], ls2[16][64];
#pragma unroll
  for (int k = 0; k < 4; ++k) { ls[rg][eq + k] = s[k]; ls2[rg][eq + k] = s2[k]; }
  __syncthreads();
  if (t < 64) {
    float S = 0.f, S2 = 0.f;
#pragma unroll
    for (int g = 0; g < 16; ++g) { S += ls[g][t]; S2 += ls2[g][t]; }
    ps[t * 512 + n * 8 + gg] = S;
    ps2[t * 512 + n * 8 + gg] = S2;
  }
}

// K6b: finalize BN stats
__global__ __launch_bounds__(64) void k_bnfin(const float* __restrict__ ps, const float* __restrict__ ps2,
                                              float* __restrict__ mu, float* __restrict__ rs) {
  const int e = threadIdx.x;
  float S = 0.f, S2 = 0.f;
  for (int g = 0; g < 512; ++g) { S += ps[e * 512 + g]; S2 += ps2[e * 512 + g]; }
  const float invN = 1.0f / (NH * (float)MM);
  float m = S * invN;
  float var = S2 * invN - m * m;
  mu[e] = m;
  rs[e] = 1.0f / sqrtf(var + 1e-5f);
}

// ---------------------------------------------------------------------------
// K7: k_crc — fused content + rel-col per (n,x), single fresh write.
// ---------------------------------------------------------------------------
__global__ __launch_bounds__(256) void k_crc(const bf16* __restrict__ ctxTb, const bf16* __restrict__ qT,
                                             const bf16* __restrict__ yhT, const bf16* __restrict__ relcb,
                                             const float* __restrict__ mu, const float* __restrict__ rs,
                                             const float* __restrict__ gamma, const float* __restrict__ beta,
                                             bf16* __restrict__ contentT) {
  int flat = blockIdx.x + (blockIdx.y << 6);
  flat = ((flat & 7) * 512) + (flat >> 3);
  const int xx = flat & 63, n = flat >> 6;
  const int bI = n >> 3, h = n & 7;
  const int tid = threadIdx.x;
  const int lane = tid & 63, wv = tid >> 6;
  const int fr = lane & 15, fq = lane >> 4;
  __shared__ __align__(16) short smem[4096 + 8448 + 4608];
  short* Qt = smem;                         // [64][64] linear, swizzled (via GLOAD16)
  bf16* Scb = (bf16*)(smem + 4096);         // [128][66] j-major, scalar-only
  bf16* Ysb = (bf16*)(smem + 4096 + 8448);  // [64][72] e-major, i XOR-swizzled
  short* DT = smem;                         // overlay on Qt after stage 1: [64][64] FRSWZ

  const size_t nb = (size_t)n * DKC * MM;

  // stage Qt via global_load_lds (rows y, 64 d each; pre-swizzled source)
  {
    const bf16* qrow = qT + ((size_t)n * MM + xx * 64) * 64;
    const int srow = lane >> 3, skc = swzsrc(lane);
#pragma unroll
    for (int cc = 0; cc < 2; ++cc) {
      const int c = wv * 2 + cc;
      const int r = c * 8 + srow;
      GLOAD16(qrow + (size_t)r * 64 + skc, &Qt[c * 512]);
    }
  }
  // Ysb = BN(yh) from yhT[n][i][xx][e] — e-contiguous reads, swizzled transpose store
#pragma unroll
  for (int l = 0; l < 16; ++l) {
    int idx = tid + l * 256;
    int i = idx >> 6, e = idx & 63;
    float val = (b2f(yhT[nb + (size_t)i * 4096 + xx * 64 + e]) - mu[e]) * rs[e] * gamma[e] + beta[e];
    Ysb[e * 72 + (i ^ (8 * (e >> 3)))] = f2b(val);
  }
  // A-fragments: relcb (stage 1) and ctxTb (content), direct from global
  bf16x8 afr[2][2], aCT[2];
#pragma unroll
  for (int mi = 0; mi < 2; ++mi)
#pragma unroll
    for (int kk = 0; kk < 2; ++kk)
      afr[mi][kk] = *(const bf16x8*)&relcb[(size_t)(wv * 32 + mi * 16 + fr) * 64 + kk * 32 + fq * 8];
#pragma unroll
  for (int kk = 0; kk < 2; ++kk)
    aCT[kk] = *(const bf16x8*)&ctxTb[(size_t)n * 4096 + (wv * 16 + fr) * 64 + kk * 32 + fq * 8];
  __syncthreads();

  // stage 1 MFMA: Sc[j][y], wave wv owns j in [wv*32, wv*32+32)
  f32x4 acc1[2][4];
#pragma unroll
  for (int mi = 0; mi < 2; ++mi)
#pragma unroll
    for (int ni = 0; ni < 4; ++ni) acc1[mi][ni] = (f32x4){0.f, 0.f, 0.f, 0.f};
  bf16x8 bq[4][2];
#pragma unroll
  for (int ni = 0; ni < 4; ++ni) {
    const int row = ni * 16 + fr;
#pragma unroll
    for (int kk = 0; kk < 2; ++kk)
      bq[ni][kk] = *(const bf16x8*)&Qt[row * 64 + FRSWZ(kk * 32 + fq * 8, fr)];
  }
#pragma unroll
  for (int mi = 0; mi < 2; ++mi)
#pragma unroll
    for (int ni = 0; ni < 4; ++ni)
#pragma unroll
      for (int kk = 0; kk < 2; ++kk)
        acc1[mi][ni] = __builtin_amdgcn_mfma_f32_16x16x32_bf16(afr[mi][kk], bq[ni][kk], acc1[mi][ni], 0, 0, 0);
#pragma unroll
  for (int mi = 0; mi < 2; ++mi)
#pragma unroll
    for (int ni = 0; ni < 4; ++ni)
#pragma unroll
      for (int r = 0; r < 4; ++r)
        Scb[(wv * 32 + mi * 16 + fq * 4 + r) * 66 + ni * 16 + fr] = f2b(acc1[mi][ni][r]);
  __syncthreads();

  // DT[y][i] = Sc[i-y+63][y], stored FRSWZ-swizzled (overlay on Qt; bq in regs)
#pragma unroll
  for (int l = 0; l < 16; ++l) {
    int idx = tid + l * 256;
    int y = idx >> 6, i = idx & 63;
    DT[y * 64 + FRSWZ(i, y)] = *(const short*)&Scb[(i - y + 63) * 66 + y];
  }
  __syncthreads();

  // acc2 = content (aCT x bq) + relcol (a2 x bd), wave wv owns e in [wv*16,+16)
  f32x4 acc2[4];
#pragma unroll
  for (int ni = 0; ni < 4; ++ni) acc2[ni] = (f32x4){0.f, 0.f, 0.f, 0.f};
#pragma unroll
  for (int ni = 0; ni < 4; ++ni)
#pragma unroll
    for (int kk = 0; kk < 2; ++kk)
      acc2[ni] = __builtin_amdgcn_mfma_f32_16x16x32_bf16(aCT[kk], bq[ni][kk], acc2[ni], 0, 0, 0);
  bf16x8 a2[2], bd[4][2];
  {
    const int row = wv * 16 + fr;
    const int swz = 8 * (row >> 3);
#pragma unroll
    for (int kk = 0; kk < 2; ++kk)
      a2[kk] = *(const bf16x8*)&Ysb[row * 72 + ((kk * 32 + fq * 8) ^ swz)];
  }
#pragma unroll
  for (int ni = 0; ni < 4; ++ni) {
    const int row = ni * 16 + fr;
#pragma unroll
    for (int kk = 0; kk < 2; ++kk)
      bd[ni][kk] = *(const bf16x8*)&DT[row * 64 + FRSWZ(kk * 32 + fq * 8, fr)];
  }
#pragma unroll
  for (int ni = 0; ni < 4; ++ni)
#pragma unroll
    for (int kk = 0; kk < 2; ++kk)
      acc2[ni] = __builtin_amdgcn_mfma_f32_16x16x32_bf16(a2[kk], bd[ni][kk], acc2[ni], 0, 0, 0);

  // single fresh write to contentT[b][m][512]
  bf16* cb = contentT + (size_t)bI * MM * 512;
#pragma unroll
  for (int ni = 0; ni < 4; ++ni) {
    size_t a = (size_t)(xx * 64 + ni * 16 + fr) * 512 + h * 64 + wv * 16 + fq * 4;
    u16x4 pk;
#pragma unroll
    for (int r = 0; r < 4; ++r) pk[r] = bbits(acc2[ni][r]);
    *(u16x4*)&cb[a] = pk;
  }
}

// ---------------------------------------------------------------------------
// K8: MFMA final GEMM, double-buffered staging, XCD-swizzled, LDS epilogue.
// ---------------------------------------------------------------------------
__global__ __launch_bounds__(256) void k_final(const bf16* __restrict__ wb2, const bf16* __restrict__ cT,
                                               const float* __restrict__ bout, float* __restrict__ dout) {
  int flat = blockIdx.x + (blockIdx.y << 5) + blockIdx.z * 64;
  flat = ((flat & 7) * 64) + (flat >> 3);        // 512 % 8 == 0, bijective
  const int bI = flat >> 6;
  const int r2 = flat & 63;
  const int o0 = (r2 >> 5) * 128;
  const int m0 = (r2 & 31) * 128;
  const int tid = threadIdx.x;
  const int lane = tid & 63, wid = tid >> 6;
  const int fr = lane & 15;
  const int fq = lane >> 4;
  const int wm = (wid >> 1) * 64, wn = (wid & 1) * 64;

  __shared__ __align__(16) short smem[32768];  // A[2][8192] | B[2][8192]; epilogue Cf

  const bf16* cB = cT + (size_t)bI * MM * 512;

  f32x4 acc[4][4];
#pragma unroll
  for (int mi = 0; mi < 4; ++mi)
#pragma unroll
    for (int ni = 0; ni < 4; ++ni) acc[mi][ni] = (f32x4){0.f, 0.f, 0.f, 0.f};

  const int srow = lane >> 3;
  const int skc = swzsrc(lane);

  // prologue: stage kt=0 into buf 0
#pragma unroll
  for (int cc = 0; cc < 4; ++cc) {
    const int c = wid * 4 + cc;
    const int r = c * 8 + srow;
    GLOAD16(wb2 + (size_t)(o0 + r) * 512 + skc, &smem[c * 512]);
    GLOAD16(cB + (size_t)(m0 + r) * 512 + skc, &smem[16384 + c * 512]);
  }
  __syncthreads();

  for (int kt = 0; kt < 8; ++kt) {
    const int buf = (kt & 1) * 8192;
    if (kt < 7) {
      const int k1 = (kt + 1) * 64;
      const int nbuf = ((kt + 1) & 1) * 8192;
#pragma unroll
      for (int cc = 0; cc < 4; ++cc) {
        const int c = wid * 4 + cc;
        const int r = c * 8 + srow;
        GLOAD16(wb2 + (size_t)(o0 + r) * 512 + k1 + skc, &smem[nbuf + c * 512]);
        GLOAD16(cB + (size_t)(m0 + r) * 512 + k1 + skc, &smem[16384 + nbuf + c * 512]);
      }
    }
    bf16x8 af[4][2], bfr[4][2];
#pragma unroll
    for (int mi = 0; mi < 4; ++mi)
#pragma unroll
      for (int kkk = 0; kkk < 2; ++kkk)
        af[mi][kkk] = *(const bf16x8*)&smem[buf + (wm + mi * 16 + fr) * 64 + FRSWZ(kkk * 32 + fq * 8, fr)];
#pragma unroll
    for (int ni = 0; ni < 4; ++ni)
#pragma unroll
      for (int kkk = 0; kkk < 2; ++kkk)
        bfr[ni][kkk] = *(const bf16x8*)&smem[16384 + buf + (wn + ni * 16 + fr) * 64 + FRSWZ(kkk * 32 + fq * 8, fr)];
#pragma unroll
    for (int mi = 0; mi < 4; ++mi)
#pragma unroll
      for (int ni = 0; ni < 4; ++ni)
#pragma unroll
        for (int kkk = 0; kkk < 2; ++kkk)
          acc[mi][ni] = __builtin_amdgcn_mfma_f32_16x16x32_bf16(af[mi][kkk], bfr[ni][kkk], acc[mi][ni], 0, 0, 0);
    __syncthreads();
  }

  float* Cf = (float*)smem;  // pitch 132 floats (16B-aligned rows)
#pragma unroll
  for (int half = 0; half < 2; ++half) {
    if ((wm >> 6) == half) {
#pragma unroll
      for (int mi = 0; mi < 4; ++mi)
#pragma unroll
        for (int ni = 0; ni < 4; ++ni)
#pragma unroll
          for (int r = 0; r < 4; ++r) {
            const int rowh = mi * 16 + fq * 4 + r;
            Cf[rowh * 132 + wn + ni * 16 + fr] = acc[mi][ni][r] + bout[o0 + half * 64 + rowh];
          }
    }
    __syncthreads();
#pragma unroll
    for (int j = 0; j < 8; ++j) {
      int f2 = tid + j * 256;
      int rowh = f2 >> 5, seg = f2 & 31;
      f32x4 pk = *(const f32x4*)&Cf[rowh * 132 + seg * 4];
      *(f32x4*)&dout[((size_t)bI * 256 + o0 + half * 64 + rowh) * MM + m0 + seg * 4] = pk;
    }
    __syncthreads();
  }
}

// ---------------------------------------------------------------------------
extern "C" void kernel_launch(void* const* d_in, const int* in_sizes, int n_in,
                              void* d_out, int out_size, void* d_ws, size_t ws_size,
                              hipStream_t stream) {
  const float* img = (const float*)d_in[0];
  const float* w_qkv = (const float*)d_in[1];
  const float* w_out = (const float*)d_in[2];
  const float* b_out = (const float*)d_in[3];
  const float* rel_rows = (const float*)d_in[4];
  const float* rel_cols = (const float*)d_in[5];
  const float* gamma = (const float*)d_in[6];
  const float* beta = (const float*)d_in[7];
  float* out = (float*)d_out;

  const size_t SZ = (size_t)NH * DKC * MM;  // 16,777,216 elements
  bf16* qbuf = (bf16*)d_ws;       // SZ bf16: qT[n][m][d]
  bf16* kbuf = qbuf + SZ;         // SZ: k -> dead -> vT
  bf16* vbuf = kbuf + SZ;         // SZ: v -> dead -> yhT [n][y][x][e]
  bf16* imgT = vbuf + SZ;         // 8,388,608 bf16, dead after k_qkv
  // union region overlaid on imgT:
  float* ctxp = (float*)imgT;     // 4*262144 f32
  float* ctx = ctxp + 4 * 262144; // (unused f32 slot, kept for layout stability)
  float* ps = ctx + 262144;       // 32768
  float* ps2 = ps + 32768;        // 32768
  float* mu = ps2 + 32768;        // 64
  float* rs = mu + 64;            // 64
  bf16* wb = imgT + 8388608;      // 393,216 bf16
  bf16* sxbuf = wb + 393216;      // SZ: sxT -> dead -> contentT [b][m][512]
  bf16* wb2 = sxbuf + SZ;         // 131,072 bf16 (w_out)
  bf16* relcb = wb2 + 131072;     // 8,192 bf16
  bf16* relrb = relcb + 8192;     // 8,192 bf16
  bf16* ctxTb = relrb + 8192;     // 262,144 bf16 (ctx^T)
  // total ~152.5 MB

  k_cvt_all<<<2112, 256, 0, stream>>>(w_qkv, w_out, rel_cols, rel_rows, wb, wb2, relcb, relrb);
  k_timg<<<dim3(64, 4, 8), 256, 0, stream>>>(img, imgT);
  k_qkv<<<dim3(32, 12, 8), 256, 0, stream>>>(wb, imgT, qbuf, kbuf, vbuf);
  k_softmax<<<4096, 256, 0, stream>>>(kbuf);
  k_ctx2<<<dim3(4, 64), 256, 0, stream>>>(kbuf, vbuf, ctxp);
  k_ctxred_T<<<64, 256, 0, stream>>>(ctxp, ctxTb);
  // rel-row path
  k_sx2<<<dim3(64, 64), 256, 0, stream>>>(relrb, qbuf, sxbuf);       // sxT
  k_vt<<<dim3(8, 64), 256, 0, stream>>>(vbuf, kbuf);                 // kbuf := vT (k dead)
  k_yh2<<<dim3(64, 64), 256, 0, stream>>>(kbuf, sxbuf, vbuf);        // vbuf := yhT (v dead)
  k_bnpart2<<<dim3(8, 64), 256, 0, stream>>>(vbuf, ps, ps2);
  k_bnfin<<<1, 64, 0, stream>>>(ps, ps2, mu, rs);
  // fused content + rel-col into contentT = sxbuf (sxT dead)
  k_crc<<<dim3(64, 64), 256, 0, stream>>>(ctxTb, qbuf, vbuf, relcb, mu, rs, gamma, beta, sxbuf);
  k_final<<<dim3(32, 2, 8), 256, 0, stream>>>(wb2, sxbuf, b_out, out);
}

// Round 16
// 199.208 us; speedup vs baseline: 1.0270x; 1.0270x over previous
//
#include <hip/hip_runtime.h>
#include <hip/hip_bf16.h>
#include <math.h>

// Problem constants
#define NH   64     // b*H heads
#define DKC  64     // dim per head
#define MM   4096   // x*y
#define CC   256    // img channels
#define RRN  127    // 2L-1

typedef __hip_bfloat16 bf16;
__device__ __forceinline__ float b2f(bf16 x) { return __bfloat162float(x); }
__device__ __forceinline__ bf16 f2b(float x) { return __float2bfloat16(x); }
__device__ __forceinline__ unsigned short bbits(float x) { bf16 h = f2b(x); return *(unsigned short*)&h; }
__device__ __forceinline__ float fbits(unsigned short u) { bf16 h = *(bf16*)&u; return b2f(h); }

typedef short bf16x8 __attribute__((ext_vector_type(8)));
typedef float f32x4 __attribute__((ext_vector_type(4)));
typedef unsigned short u16;
typedef u16 u16x4 __attribute__((ext_vector_type(4)));
typedef u16 u16x8 __attribute__((ext_vector_type(8)));

#define AS1 __attribute__((address_space(1)))
#define AS3 __attribute__((address_space(3)))
#define GLOAD16(gp, lp) __builtin_amdgcn_global_load_lds((const AS1 void*)(gp), (AS3 void*)(lp), 16, 0, 0)

// swizzled source elem offset for staging (involution partner of FRSWZ)
__device__ __forceinline__ int swzsrc(int lane) { return 8 * ((lane & 7) ^ (lane >> 3)); }
// fragment-read elem index within a 64-elem row, row-swizzled
#define FRSWZ(kelem, row) ((kelem) ^ (((row) & 7) * 8))

// ---------------------------------------------------------------------------
// K0a: merged converts. grid 2112 x 256 covers 540672 slots.
// ---------------------------------------------------------------------------
__global__ __launch_bounds__(256) void k_cvt_all(const float* __restrict__ w_qkv, const float* __restrict__ w_out,
                                                 const float* __restrict__ relc, const float* __restrict__ relr,
                                                 bf16* __restrict__ wb, bf16* __restrict__ wb2,
                                                 bf16* __restrict__ relcb, bf16* __restrict__ relrb) {
  const int i = blockIdx.x * 256 + threadIdx.x;
  if (i < 393216) {
    wb[i] = f2b(w_qkv[i]);
  } else if (i < 524288) {
    int j = i - 393216; wb2[j] = f2b(w_out[j]);
  } else if (i < 532480) {
    int j = i - 524288; relcb[j] = (j < RRN * 64) ? f2b(relc[j]) : f2b(0.f);
  } else {
    int j = i - 532480; if (j < RRN * 64) relrb[j] = f2b(relr[j]);
  }
}

// ---------------------------------------------------------------------------
// K0b: img fp32 [8][256][4096] -> bf16 imgT [8][4096][256], vectorized
// ---------------------------------------------------------------------------
__global__ __launch_bounds__(256) void k_timg(const float* __restrict__ img, bf16* __restrict__ imgT) {
  const int b = blockIdx.z, c0 = blockIdx.y * 64, m0 = blockIdx.x * 64;
  const int tid = threadIdx.x;
  __shared__ short T[64 * 66];
  const float* ib = img + ((size_t)b * CC + c0) * MM + m0;
#pragma unroll
  for (int j = 0; j < 4; ++j) {
    int f4 = j * 256 + tid;          // 0..1023
    int cc = f4 >> 4, mm4 = (f4 & 15) * 4;
    f32x4 v = *(const f32x4*)&ib[(size_t)cc * MM + mm4];
#pragma unroll
    for (int k = 0; k < 4; ++k) T[cc * 66 + mm4 + k] = (short)bbits(v[k]);
  }
  __syncthreads();
  bf16* ob = imgT + ((size_t)b * MM + m0) * CC + c0;
#pragma unroll
  for (int j = 0; j < 4; ++j) {
    int f4 = j * 256 + tid;
    int mm = f4 >> 4, cc4 = (f4 & 15) * 4;
    u16x4 pk;
#pragma unroll
    for (int k = 0; k < 4; ++k) pk[k] = (u16)T[(cc4 + k) * 66 + mm];
    *(u16x4*)&ob[(size_t)mm * CC + cc4] = pk;
  }
}

// ---------------------------------------------------------------------------
// K1: MFMA qkv GEMM (128x128 tile, BK=64, 4 waves), A+B LDS-staged, swizzled.
// (round-14 proven form: 41 us) Epilogue: C-tile reassembled in LDS, u16x8 out.
// ---------------------------------------------------------------------------
__global__ __launch_bounds__(256) void k_qkv(const bf16* __restrict__ wb, const bf16* __restrict__ imgT,
                                             bf16* __restrict__ qT, bf16* __restrict__ kk, bf16* __restrict__ v) {
  const int bI = blockIdx.z;
  const int o0 = blockIdx.y * 128;
  const int m0 = blockIdx.x * 128;
  const int tid = threadIdx.x;
  const int lane = tid & 63, wid = tid >> 6;
  const int fr = lane & 15;
  const int fq = lane >> 4;
  const int wm = (wid >> 1) * 64, wn = (wid & 1) * 64;

  __shared__ __align__(16) short smem[17408];  // As[8192] | Bs[8192]; epilogue: Cs[128][136]
  short* As = smem;
  short* Bs = smem + 8192;

  const bf16* iB = imgT + (size_t)bI * MM * CC;

  f32x4 acc[4][4];
#pragma unroll
  for (int mi = 0; mi < 4; ++mi)
#pragma unroll
    for (int ni = 0; ni < 4; ++ni) acc[mi][ni] = (f32x4){0.f, 0.f, 0.f, 0.f};

  const int srow = lane >> 3;
  const int skc = swzsrc(lane);

  for (int kt = 0; kt < 4; ++kt) {
    const int k0 = kt * 64;
#pragma unroll
    for (int cc = 0; cc < 4; ++cc) {
      const int c = wid * 4 + cc;
      const int r = c * 8 + srow;
      GLOAD16(wb + (size_t)(o0 + r) * CC + k0 + skc, &As[c * 512]);
      GLOAD16(iB + (size_t)(m0 + r) * CC + k0 + skc, &Bs[c * 512]);
    }
    __syncthreads();
    bf16x8 af[4][2], bfr[4][2];
#pragma unroll
    for (int mi = 0; mi < 4; ++mi)
#pragma unroll
      for (int kkk = 0; kkk < 2; ++kkk)
        af[mi][kkk] = *(const bf16x8*)&As[(wm + mi * 16 + fr) * 64 + FRSWZ(kkk * 32 + fq * 8, fr)];
#pragma unroll
    for (int ni = 0; ni < 4; ++ni)
#pragma unroll
      for (int kkk = 0; kkk < 2; ++kkk)
        bfr[ni][kkk] = *(const bf16x8*)&Bs[(wn + ni * 16 + fr) * 64 + FRSWZ(kkk * 32 + fq * 8, fr)];
#pragma unroll
    for (int mi = 0; mi < 4; ++mi)
#pragma unroll
      for (int ni = 0; ni < 4; ++ni)
#pragma unroll
        for (int kkk = 0; kkk < 2; ++kkk)
          acc[mi][ni] = __builtin_amdgcn_mfma_f32_16x16x32_bf16(af[mi][kkk], bfr[ni][kkk], acc[mi][ni], 0, 0, 0);
    __syncthreads();
  }

  short* Cs = smem;  // pitch 136 (16B-aligned rows, bank-shifted)
  if (o0 < 512) {
    // q path: store transposed Cs[m][o] so d is contiguous on output
#pragma unroll
    for (int mi = 0; mi < 4; ++mi)
#pragma unroll
      for (int ni = 0; ni < 4; ++ni)
#pragma unroll
        for (int r = 0; r < 4; ++r)
          Cs[(wn + ni * 16 + fr) * 136 + wm + mi * 16 + fq * 4 + r] = (short)bbits(acc[mi][ni][r]);
    __syncthreads();
    const int n0 = bI * 8 + (o0 >> 6);
#pragma unroll
    for (int j = 0; j < 8; ++j) {
      int flat = tid + j * 256;
      int m = flat >> 4, nh = (flat >> 3) & 1, ds = flat & 7;
      u16x8 pk = *(const u16x8*)&Cs[m * 136 + nh * 64 + ds * 8];
      *(u16x8*)&qT[((size_t)(n0 + nh) * MM + m0 + m) * 64 + ds * 8] = pk;
    }
  } else {
    // k/v path: Cs[o][m], rows contiguous on output
#pragma unroll
    for (int mi = 0; mi < 4; ++mi)
#pragma unroll
      for (int ni = 0; ni < 4; ++ni)
#pragma unroll
        for (int r = 0; r < 4; ++r)
          Cs[(wm + mi * 16 + fq * 4 + r) * 136 + wn + ni * 16 + fr] = (short)bbits(acc[mi][ni][r]);
    __syncthreads();
    bf16* dst = (o0 < 1024) ? kk : v;
    const int obase = (o0 < 1024) ? (o0 - 512) : (o0 - 1024);
#pragma unroll
    for (int j = 0; j < 8; ++j) {
      int flat = tid + j * 256;
      int row = flat >> 4, seg = flat & 15;
      u16x8 pk = *(const u16x8*)&Cs[row * 136 + seg * 8];
      *(u16x8*)&dst[((size_t)bI * 512 + obase + row) * MM + m0 + seg * 8] = pk;
    }
  }
}

// ---------------------------------------------------------------------------
// K2: in-place softmax, row cached in registers: 1 read + 1 write
// ---------------------------------------------------------------------------
__global__ __launch_bounds__(256) void k_softmax(bf16* __restrict__ kk) {
  const size_t row = blockIdx.x;
  bf16* p = kk + row * (size_t)MM;
  const int t = threadIdx.x;
  __shared__ float sred[4];
  float v[16];
  float mx = -1e30f;
#pragma unroll
  for (int j = 0; j < 4; ++j) {
    u16x4 v4 = *(const u16x4*)&p[(j * 256 + t) * 4];
#pragma unroll
    for (int k = 0; k < 4; ++k) { v[j * 4 + k] = fbits(v4[k]); mx = fmaxf(mx, v[j * 4 + k]); }
  }
#pragma unroll
  for (int off = 32; off; off >>= 1) mx = fmaxf(mx, __shfl_down(mx, off));
  if ((t & 63) == 0) sred[t >> 6] = mx;
  __syncthreads();
  mx = fmaxf(fmaxf(sred[0], sred[1]), fmaxf(sred[2], sred[3]));
  __syncthreads();
  float s = 0.f;
#pragma unroll
  for (int i = 0; i < 16; ++i) { v[i] = expf(v[i] - mx); s += v[i]; }
#pragma unroll
  for (int off = 32; off; off >>= 1) s += __shfl_down(s, off);
  if ((t & 63) == 0) sred[t >> 6] = s;
  __syncthreads();
  s = sred[0] + sred[1] + sred[2] + sred[3];
  const float inv = 1.0f / s;
#pragma unroll
  for (int j = 0; j < 4; ++j) {
    u16x4 o;
#pragma unroll
    for (int k = 0; k < 4; ++k) o[k] = bbits(v[j * 4 + k] * inv);
    *(u16x4*)&p[(j * 256 + t) * 4] = o;
  }
}

// ---------------------------------------------------------------------------
// K3a: MFMA ctx: part[ch][n][d][e] = sum_{m in chunk} k[n,d,m]*v[n,e,m]
// ---------------------------------------------------------------------------
__global__ __launch_bounds__(256) void k_ctx2(const bf16* __restrict__ kk, const bf16* __restrict__ v,
                                              float* __restrict__ part) {
  const int ch = blockIdx.x, n = blockIdx.y;
  const int tid = threadIdx.x;
  const int lane = tid & 63, wid = tid >> 6;
  const int fr = lane & 15, fq = lane >> 4;
  const int wr = (wid >> 1) * 32, wc = (wid & 1) * 32;
  __shared__ __align__(16) short Ks[64 * 64];
  __shared__ __align__(16) short Vs[64 * 64];
  const bf16* kp = kk + (size_t)n * DKC * MM;
  const bf16* vp = v + (size_t)n * DKC * MM;
  const int srow = lane >> 3;
  const int skc = swzsrc(lane);

  f32x4 acc[2][2];
#pragma unroll
  for (int mi = 0; mi < 2; ++mi)
#pragma unroll
    for (int ni = 0; ni < 2; ++ni) acc[mi][ni] = (f32x4){0.f, 0.f, 0.f, 0.f};

  for (int t = 0; t < 16; ++t) {
    const int m0 = ch * 1024 + t * 64;
#pragma unroll
    for (int cc = 0; cc < 4; ++cc) {
      const int c = wid * 4 + cc;
      if (c < 8) {
        const int r = c * 8 + srow;
        GLOAD16(kp + (size_t)r * MM + m0 + skc, &Ks[c * 512]);
      } else {
        const int r = (c - 8) * 8 + srow;
        GLOAD16(vp + (size_t)r * MM + m0 + skc, &Vs[(c - 8) * 512]);
      }
    }
    __syncthreads();
    bf16x8 af[2][2], bf[2][2];
#pragma unroll
    for (int mi = 0; mi < 2; ++mi)
#pragma unroll
      for (int kkx = 0; kkx < 2; ++kkx)
        af[mi][kkx] = *(const bf16x8*)&Ks[(wr + mi * 16 + fr) * 64 + FRSWZ(kkx * 32 + fq * 8, fr)];
#pragma unroll
    for (int ni = 0; ni < 2; ++ni)
#pragma unroll
      for (int kkx = 0; kkx < 2; ++kkx)
        bf[ni][kkx] = *(const bf16x8*)&Vs[(wc + ni * 16 + fr) * 64 + FRSWZ(kkx * 32 + fq * 8, fr)];
#pragma unroll
    for (int mi = 0; mi < 2; ++mi)
#pragma unroll
      for (int ni = 0; ni < 2; ++ni)
#pragma unroll
        for (int kkx = 0; kkx < 2; ++kkx)
          acc[mi][ni] = __builtin_amdgcn_mfma_f32_16x16x32_bf16(af[mi][kkx], bf[ni][kkx], acc[mi][ni], 0, 0, 0);
    __syncthreads();
  }
  float* pb = part + ((size_t)ch * NH + n) * 4096;
#pragma unroll
  for (int mi = 0; mi < 2; ++mi)
#pragma unroll
    for (int ni = 0; ni < 2; ++ni)
#pragma unroll
      for (int r = 0; r < 4; ++r)
        pb[(wr + mi * 16 + fq * 4 + r) * 64 + wc + ni * 16 + fr] = acc[mi][ni][r];
}

// K3b: reduce 4 partials + transpose + convert: part -> ctxTb[n][e][d] bf16
__global__ __launch_bounds__(256) void k_ctxred_T(const float* __restrict__ part, bf16* __restrict__ ctxTb) {
  const int n = blockIdx.x;
  const int tid = threadIdx.x;
  __shared__ float T[64 * 67];  // T[d][e]
  const float* pn = part + (size_t)n * 4096;
#pragma unroll
  for (int l = 0; l < 16; ++l) {
    int idx = tid + l * 256;
    int d = idx >> 6, e = idx & 63;
    float s = 0.f;
#pragma unroll
    for (int c = 0; c < 4; ++c) s += pn[(size_t)c * 262144 + idx];
    T[d * 67 + e] = s;
  }
  __syncthreads();
  bf16* ob = ctxTb + (size_t)n * 4096;
#pragma unroll
  for (int l = 0; l < 4; ++l) {
    int q = tid + l * 256;
    int e = q >> 4, d4 = (q & 15) * 4;
    u16x4 pk;
#pragma unroll
    for (int k = 0; k < 4; ++k) pk[k] = bbits(T[(d4 + k) * 67 + e]);
    *(u16x4*)&ob[e * 64 + d4] = pk;
  }
}

// ---------------------------------------------------------------------------
// K5a: MFMA k_sx2: sxT[n][y][x][i] = sum_d relr[i+63-x][d]*qT[n][x*64+y][d]
// ---------------------------------------------------------------------------
__global__ __launch_bounds__(256) void k_sx2(const bf16* __restrict__ relrb, const bf16* __restrict__ qT,
                                             bf16* __restrict__ sxT) {
  const int x = blockIdx.x, n = blockIdx.y;
  const int tid = threadIdx.x;
  const int lane = tid & 63, wid = tid >> 6;
  const int fr = lane & 15, fq = lane >> 4;
  const int wr = (wid >> 1) * 32, wc = (wid & 1) * 32;  // wr: i, wc: y
  __shared__ __align__(16) short Qt[64 * 64];   // Qt[y][d], swizzled
  const bf16* qrow = qT + ((size_t)n * MM + x * 64) * 64;
  const int srow = lane >> 3, skc = swzsrc(lane);
#pragma unroll
  for (int cc = 0; cc < 2; ++cc) {
    const int c = wid * 2 + cc;          // 0..7
    const int r = c * 8 + srow;          // y row
    GLOAD16(qrow + (size_t)r * 64 + skc, &Qt[c * 512]);
  }
  bf16x8 af[2][2];
#pragma unroll
  for (int mi = 0; mi < 2; ++mi) {
    const int j = wr + mi * 16 + fr + 63 - x;
#pragma unroll
    for (int kk = 0; kk < 2; ++kk)
      af[mi][kk] = *(const bf16x8*)&relrb[(size_t)j * 64 + kk * 32 + fq * 8];
  }
  __syncthreads();
  bf16x8 bq[2][2];
#pragma unroll
  for (int ni = 0; ni < 2; ++ni) {
    const int row = wc + ni * 16 + fr;
#pragma unroll
    for (int kk = 0; kk < 2; ++kk)
      bq[ni][kk] = *(const bf16x8*)&Qt[row * 64 + FRSWZ(kk * 32 + fq * 8, fr)];
  }
  f32x4 acc[2][2];
#pragma unroll
  for (int mi = 0; mi < 2; ++mi)
#pragma unroll
    for (int ni = 0; ni < 2; ++ni) acc[mi][ni] = (f32x4){0.f, 0.f, 0.f, 0.f};
#pragma unroll
  for (int mi = 0; mi < 2; ++mi)
#pragma unroll
    for (int ni = 0; ni < 2; ++ni)
#pragma unroll
      for (int kk = 0; kk < 2; ++kk)
        acc[mi][ni] = __builtin_amdgcn_mfma_f32_16x16x32_bf16(af[mi][kk], bq[ni][kk], acc[mi][ni], 0, 0, 0);
  // D[row=i][col=y] -> sxT[n][y][x][i], 4 consecutive i per store
#pragma unroll
  for (int mi = 0; mi < 2; ++mi)
#pragma unroll
    for (int ni = 0; ni < 2; ++ni) {
      const int yy2 = wc + ni * 16 + fr;
      u16x4 pk;
#pragma unroll
      for (int r = 0; r < 4; ++r) pk[r] = bbits(acc[mi][ni][r]);
      *(u16x4*)&sxT[(((size_t)n * 64 + yy2) * 64 + x) * 64 + wr + mi * 16 + fq * 4] = pk;
    }
}

// ---------------------------------------------------------------------------
// K5v: k_vt — transpose v[n][e][x][y] -> vT[n][y][e][x]
// ---------------------------------------------------------------------------
__global__ __launch_bounds__(256) void k_vt(const bf16* __restrict__ v, bf16* __restrict__ vT) {
  const int eg = blockIdx.x, n = blockIdx.y;
  const int tid = threadIdx.x;
  __shared__ short T[8 * 64 * 66];  // T[e][y][x], pitch 66
  const bf16* vp = v + (size_t)n * DKC * MM + (size_t)eg * 8 * MM;
#pragma unroll
  for (int j = 0; j < 16; ++j) {
    int flat = (j * 256 + tid) * 8;
    int e = flat >> 12, m = flat & 4095;
    int x = m >> 6, y0 = m & 63;
    u16x4 lo = *(const u16x4*)&vp[(size_t)e * MM + m];
    u16x4 hi = *(const u16x4*)&vp[(size_t)e * MM + m + 4];
#pragma unroll
    for (int k = 0; k < 4; ++k) T[(e * 64 + y0 + k) * 66 + x] = (short)lo[k];
#pragma unroll
    for (int k = 0; k < 4; ++k) T[(e * 64 + y0 + 4 + k) * 66 + x] = (short)hi[k];
  }
  __syncthreads();
#pragma unroll
  for (int j = 0; j < 32; ++j) {
    int flat4 = j * 256 + tid;            // 8192 quads
    int x4 = flat4 & 15, e = (flat4 >> 4) & 7, y = flat4 >> 7;
    u16x4 pk;
#pragma unroll
    for (int r = 0; r < 4; ++r) pk[r] = (u16)T[(e * 64 + y) * 66 + x4 * 4 + r];
    *(u16x4*)&vT[(((size_t)n * 64 + y) * 64 + eg * 8 + e) * 64 + x4 * 4] = pk;
  }
}

// ---------------------------------------------------------------------------
// K5b: k_yh2 — MFMA per (n,y): yhT[n][y][x][e] = sum_i vT[n][y][e][i]*sxT[n][y][x][i]
// ---------------------------------------------------------------------------
__global__ __launch_bounds__(256) void k_yh2(const bf16* __restrict__ vT, const bf16* __restrict__ sxT,
                                             bf16* __restrict__ yhT) {
  const int y = blockIdx.x, n = blockIdx.y;
  const int tid = threadIdx.x;
  const int lane = tid & 63, wid = tid >> 6;
  const int fr = lane & 15, fq = lane >> 4;
  const int wr = (wid >> 1) * 32, wc = (wid & 1) * 32;  // wr: e, wc: x
  __shared__ __align__(16) short Va[64 * 64];
  __shared__ __align__(16) short Sa[64 * 64];
  const size_t rb = ((size_t)n * 64 + y) * 4096;
  const int srow = lane >> 3;
  const int skc = swzsrc(lane);
#pragma unroll
  for (int cc = 0; cc < 2; ++cc) {
    const int c = wid * 2 + cc;
    const int r = c * 8 + srow;
    GLOAD16(vT + rb + (size_t)r * 64 + skc, &Va[c * 512]);
    GLOAD16(sxT + rb + (size_t)r * 64 + skc, &Sa[c * 512]);
  }
  __syncthreads();
  bf16x8 av[2][2], bs[2][2];
#pragma unroll
  for (int mi = 0; mi < 2; ++mi)
#pragma unroll
    for (int kk = 0; kk < 2; ++kk)
      av[mi][kk] = *(const bf16x8*)&Va[(wr + mi * 16 + fr) * 64 + FRSWZ(kk * 32 + fq * 8, fr)];
#pragma unroll
  for (int ni = 0; ni < 2; ++ni)
#pragma unroll
    for (int kk = 0; kk < 2; ++kk)
      bs[ni][kk] = *(const bf16x8*)&Sa[(wc + ni * 16 + fr) * 64 + FRSWZ(kk * 32 + fq * 8, fr)];
  f32x4 acc[2][2];
#pragma unroll
  for (int mi = 0; mi < 2; ++mi)
#pragma unroll
    for (int ni = 0; ni < 2; ++ni) acc[mi][ni] = (f32x4){0.f, 0.f, 0.f, 0.f};
#pragma unroll
  for (int mi = 0; mi < 2; ++mi)
#pragma unroll
    for (int ni = 0; ni < 2; ++ni)
#pragma unroll
      for (int kk = 0; kk < 2; ++kk)
        acc[mi][ni] = __builtin_amdgcn_mfma_f32_16x16x32_bf16(av[mi][kk], bs[ni][kk], acc[mi][ni], 0, 0, 0);
#pragma unroll
  for (int mi = 0; mi < 2; ++mi)
#pragma unroll
    for (int ni = 0; ni < 2; ++ni) {
      const int xo = wc + ni * 16 + fr;
      u16x4 pk;
#pragma unroll
      for (int r = 0; r < 4; ++r) pk[r] = bbits(acc[mi][ni][r]);
      *(u16x4*)&yhT[rb + (size_t)xo * 64 + wr + mi * 16 + fq * 4] = pk;
    }
}

// ---------------------------------------------------------------------------
// K6a: BN partial stats from yhT. grid (8 row-groups, 64 n)
// ---------------------------------------------------------------------------
__global__ __launch_bounds__(256) void k_bnpart2(const bf16* __restrict__ yhT, float* __restrict__ ps,
                                                 float* __restrict__ ps2) {
  const int gg = blockIdx.x, n = blockIdx.y;
  const int t = threadIdx.x;
  const int eq = (t & 15) * 4, rg = t >> 4;
  const bf16* p = yhT + (size_t)n * 262144 + (size_t)gg * 512 * 64;
  float s[4] = {}, s2[4] = {};
  for (int r = rg; r < 512; r += 16) {
    u16x4 v4 = *(const u16x4*)&p[(size_t)r * 64 + eq];
#pragma unroll
    for (int k = 0; k < 4; ++k) { float x = fbits(v4[k]); s[k] += x; s2[k] += x * x; }
  }
  __shared__ float ls[16][64], ls2[16][64];
#pragma unroll
  for (int k = 0; k < 4; ++k) { ls[rg][eq + k] = s[k]; ls2[rg][eq + k] = s2[k]; }
  __syncthreads();
  if (t < 64) {
    float S = 0.f, S2 = 0.f;
#pragma unroll
    for (int g = 0; g < 16; ++g) { S += ls[g][t]; S2 += ls2[g][t]; }
    ps[t * 512 + n * 8 + gg] = S;
    ps2[t * 512 + n * 8 + gg] = S2;
  }
}

// K6b: finalize BN stats
__global__ __launch_bounds__(64) void k_bnfin(const float* __restrict__ ps, const float* __restrict__ ps2,
                                              float* __restrict__ mu, float* __restrict__ rs) {
  const int e = threadIdx.x;
  float S = 0.f, S2 = 0.f;
  for (int g = 0; g < 512; ++g) { S += ps[e * 512 + g]; S2 += ps2[e * 512 + g]; }
  const float invN = 1.0f / (NH * (float)MM);
  float m = S * invN;
  float var = S2 * invN - m * m;
  mu[e] = m;
  rs[e] = 1.0f / sqrtf(var + 1e-5f);
}

// ---------------------------------------------------------------------------
// K7: k_crc — fused content + rel-col per (n,x), single fresh write.
// ---------------------------------------------------------------------------
__global__ __launch_bounds__(256) void k_crc(const bf16* __restrict__ ctxTb, const bf16* __restrict__ qT,
                                             const bf16* __restrict__ yhT, const bf16* __restrict__ relcb,
                                             const float* __restrict__ mu, const float* __restrict__ rs,
                                             const float* __restrict__ gamma, const float* __restrict__ beta,
                                             bf16* __restrict__ contentT) {
  const int xx = blockIdx.x, n = blockIdx.y;
  const int bI = n >> 3, h = n & 7;
  const int tid = threadIdx.x;
  const int lane = tid & 63, wv = tid >> 6;
  const int fr = lane & 15, fq = lane >> 4;
  __shared__ __align__(16) short smem[4096 + 8448 + 4608];
  short* Qt = smem;                         // [64][64] linear, swizzled (via GLOAD16)
  bf16* Scb = (bf16*)(smem + 4096);         // [128][66] j-major, scalar-only
  bf16* Ysb = (bf16*)(smem + 4096 + 8448);  // [64][72] e-major, i XOR-swizzled
  short* DT = smem;                         // overlay on Qt after stage 1: [64][64] FRSWZ

  const size_t nb = (size_t)n * DKC * MM;

  // stage Qt via global_load_lds (rows y, 64 d each; pre-swizzled source)
  {
    const bf16* qrow = qT + ((size_t)n * MM + xx * 64) * 64;
    const int srow = lane >> 3, skc = swzsrc(lane);
#pragma unroll
    for (int cc = 0; cc < 2; ++cc) {
      const int c = wv * 2 + cc;
      const int r = c * 8 + srow;
      GLOAD16(qrow + (size_t)r * 64 + skc, &Qt[c * 512]);
    }
  }
  // Ysb = BN(yh) from yhT[n][i][xx][e] — e-contiguous reads, swizzled transpose store
#pragma unroll
  for (int l = 0; l < 16; ++l) {
    int idx = tid + l * 256;
    int i = idx >> 6, e = idx & 63;
    float val = (b2f(yhT[nb + (size_t)i * 4096 + xx * 64 + e]) - mu[e]) * rs[e] * gamma[e] + beta[e];
    Ysb[e * 72 + (i ^ (8 * (e >> 3)))] = f2b(val);
  }
  // A-fragments: relcb (stage 1) and ctxTb (content), direct from global
  bf16x8 afr[2][2], aCT[2];
#pragma unroll
  for (int mi = 0; mi < 2; ++mi)
#pragma unroll
    for (int kk = 0; kk < 2; ++kk)
      afr[mi][kk] = *(const bf16x8*)&relcb[(size_t)(wv * 32 + mi * 16 + fr) * 64 + kk * 32 + fq * 8];
#pragma unroll
  for (int kk = 0; kk < 2; ++kk)
    aCT[kk] = *(const bf16x8*)&ctxTb[(size_t)n * 4096 + (wv * 16 + fr) * 64 + kk * 32 + fq * 8];
  __syncthreads();

  // stage 1 MFMA: Sc[j][y], wave wv owns j in [wv*32, wv*32+32)
  f32x4 acc1[2][4];
#pragma unroll
  for (int mi = 0; mi < 2; ++mi)
#pragma unroll
    for (int ni = 0; ni < 4; ++ni) acc1[mi][ni] = (f32x4){0.f, 0.f, 0.f, 0.f};
  bf16x8 bq[4][2];
#pragma unroll
  for (int ni = 0; ni < 4; ++ni) {
    const int row = ni * 16 + fr;
#pragma unroll
    for (int kk = 0; kk < 2; ++kk)
      bq[ni][kk] = *(const bf16x8*)&Qt[row * 64 + FRSWZ(kk * 32 + fq * 8, fr)];
  }
#pragma unroll
  for (int mi = 0; mi < 2; ++mi)
#pragma unroll
    for (int ni = 0; ni < 4; ++ni)
#pragma unroll
      for (int kk = 0; kk < 2; ++kk)
        acc1[mi][ni] = __builtin_amdgcn_mfma_f32_16x16x32_bf16(afr[mi][kk], bq[ni][kk], acc1[mi][ni], 0, 0, 0);
#pragma unroll
  for (int mi = 0; mi < 2; ++mi)
#pragma unroll
    for (int ni = 0; ni < 4; ++ni)
#pragma unroll
      for (int r = 0; r < 4; ++r)
        Scb[(wv * 32 + mi * 16 + fq * 4 + r) * 66 + ni * 16 + fr] = f2b(acc1[mi][ni][r]);
  __syncthreads();

  // DT[y][i] = Sc[i-y+63][y], stored FRSWZ-swizzled (overlay on Qt; bq in regs)
#pragma unroll
  for (int l = 0; l < 16; ++l) {
    int idx = tid + l * 256;
    int y = idx >> 6, i = idx & 63;
    DT[y * 64 + FRSWZ(i, y)] = *(const short*)&Scb[(i - y + 63) * 66 + y];
  }
  __syncthreads();

  // acc2 = content (aCT x bq) + relcol (a2 x bd), wave wv owns e in [wv*16,+16)
  f32x4 acc2[4];
#pragma unroll
  for (int ni = 0; ni < 4; ++ni) acc2[ni] = (f32x4){0.f, 0.f, 0.f, 0.f};
#pragma unroll
  for (int ni = 0; ni < 4; ++ni)
#pragma unroll
    for (int kk = 0; kk < 2; ++kk)
      acc2[ni] = __builtin_amdgcn_mfma_f32_16x16x32_bf16(aCT[kk], bq[ni][kk], acc2[ni], 0, 0, 0);
  bf16x8 a2[2], bd[4][2];
  {
    const int row = wv * 16 + fr;
    const int swz = 8 * (row >> 3);
#pragma unroll
    for (int kk = 0; kk < 2; ++kk)
      a2[kk] = *(const bf16x8*)&Ysb[row * 72 + ((kk * 32 + fq * 8) ^ swz)];
  }
#pragma unroll
  for (int ni = 0; ni < 4; ++ni) {
    const int row = ni * 16 + fr;
#pragma unroll
    for (int kk = 0; kk < 2; ++kk)
      bd[ni][kk] = *(const bf16x8*)&DT[row * 64 + FRSWZ(kk * 32 + fq * 8, fr)];
  }
#pragma unroll
  for (int ni = 0; ni < 4; ++ni)
#pragma unroll
    for (int kk = 0; kk < 2; ++kk)
      acc2[ni] = __builtin_amdgcn_mfma_f32_16x16x32_bf16(a2[kk], bd[ni][kk], acc2[ni], 0, 0, 0);

  // single fresh write to contentT[b][m][512]
  bf16* cb = contentT + (size_t)bI * MM * 512;
#pragma unroll
  for (int ni = 0; ni < 4; ++ni) {
    size_t a = (size_t)(xx * 64 + ni * 16 + fr) * 512 + h * 64 + wv * 16 + fq * 4;
    u16x4 pk;
#pragma unroll
    for (int r = 0; r < 4; ++r) pk[r] = bbits(acc2[ni][r]);
    *(u16x4*)&cb[a] = pk;
  }
}

// ---------------------------------------------------------------------------
// K8: MFMA final GEMM, A+B LDS-staged, swizzled (round-14 form). Epilogue:
// LDS reassembly, two 64-row halves, coalesced f32x4 stores with bias.
// ---------------------------------------------------------------------------
__global__ __launch_bounds__(256) void k_final(const bf16* __restrict__ wb2, const bf16* __restrict__ cT,
                                               const float* __restrict__ bout, float* __restrict__ dout) {
  const int bI = blockIdx.z;
  const int o0 = blockIdx.y * 128;
  const int m0 = blockIdx.x * 128;
  const int tid = threadIdx.x;
  const int lane = tid & 63, wid = tid >> 6;
  const int fr = lane & 15;
  const int fq = lane >> 4;
  const int wm = (wid >> 1) * 64, wn = (wid & 1) * 64;

  __shared__ __align__(16) short smem[17408];  // As|Bs; epilogue: Cf[64][132] f32
  short* As = smem;
  short* Bs = smem + 8192;

  const bf16* cB = cT + (size_t)bI * MM * 512;

  f32x4 acc[4][4];
#pragma unroll
  for (int mi = 0; mi < 4; ++mi)
#pragma unroll
    for (int ni = 0; ni < 4; ++ni) acc[mi][ni] = (f32x4){0.f, 0.f, 0.f, 0.f};

  const int srow = lane >> 3;
  const int skc = swzsrc(lane);

  for (int kt = 0; kt < 8; ++kt) {
    const int k0 = kt * 64;
#pragma unroll
    for (int cc = 0; cc < 4; ++cc) {
      const int c = wid * 4 + cc;
      const int r = c * 8 + srow;
      GLOAD16(wb2 + (size_t)(o0 + r) * 512 + k0 + skc, &As[c * 512]);
      GLOAD16(cB + (size_t)(m0 + r) * 512 + k0 + skc, &Bs[c * 512]);
    }
    __syncthreads();
    bf16x8 af[4][2], bfr[4][2];
#pragma unroll
    for (int mi = 0; mi < 4; ++mi)
#pragma unroll
      for (int kkk = 0; kkk < 2; ++kkk)
        af[mi][kkk] = *(const bf16x8*)&As[(wm + mi * 16 + fr) * 64 + FRSWZ(kkk * 32 + fq * 8, fr)];
#pragma unroll
    for (int ni = 0; ni < 4; ++ni)
#pragma unroll
      for (int kkk = 0; kkk < 2; ++kkk)
        bfr[ni][kkk] = *(const bf16x8*)&Bs[(wn + ni * 16 + fr) * 64 + FRSWZ(kkk * 32 + fq * 8, fr)];
#pragma unroll
    for (int mi = 0; mi < 4; ++mi)
#pragma unroll
      for (int ni = 0; ni < 4; ++ni)
#pragma unroll
        for (int kkk = 0; kkk < 2; ++kkk)
          acc[mi][ni] = __builtin_amdgcn_mfma_f32_16x16x32_bf16(af[mi][kkk], bfr[ni][kkk], acc[mi][ni], 0, 0, 0);
    __syncthreads();
  }

  float* Cf = (float*)smem;  // pitch 132 floats (16B-aligned rows)
#pragma unroll
  for (int half = 0; half < 2; ++half) {
    if ((wm >> 6) == half) {
#pragma unroll
      for (int mi = 0; mi < 4; ++mi)
#pragma unroll
        for (int ni = 0; ni < 4; ++ni)
#pragma unroll
          for (int r = 0; r < 4; ++r) {
            const int rowh = mi * 16 + fq * 4 + r;
            Cf[rowh * 132 + wn + ni * 16 + fr] = acc[mi][ni][r] + bout[o0 + half * 64 + rowh];
          }
    }
    __syncthreads();
#pragma unroll
    for (int j = 0; j < 8; ++j) {
      int flat = tid + j * 256;
      int rowh = flat >> 5, seg = flat & 31;
      f32x4 pk = *(const f32x4*)&Cf[rowh * 132 + seg * 4];
      *(f32x4*)&dout[((size_t)bI * 256 + o0 + half * 64 + rowh) * MM + m0 + seg * 4] = pk;
    }
    __syncthreads();
  }
}

// ---------------------------------------------------------------------------
extern "C" void kernel_launch(void* const* d_in, const int* in_sizes, int n_in,
                              void* d_out, int out_size, void* d_ws, size_t ws_size,
                              hipStream_t stream) {
  const float* img = (const float*)d_in[0];
  const float* w_qkv = (const float*)d_in[1];
  const float* w_out = (const float*)d_in[2];
  const float* b_out = (const float*)d_in[3];
  const float* rel_rows = (const float*)d_in[4];
  const float* rel_cols = (const float*)d_in[5];
  const float* gamma = (const float*)d_in[6];
  const float* beta = (const float*)d_in[7];
  float* out = (float*)d_out;

  const size_t SZ = (size_t)NH * DKC * MM;  // 16,777,216 elements
  bf16* qbuf = (bf16*)d_ws;       // SZ bf16: qT[n][m][d]
  bf16* kbuf = qbuf + SZ;         // SZ: k -> dead -> vT
  bf16* vbuf = kbuf + SZ;         // SZ: v -> dead -> yhT [n][y][x][e]
  bf16* imgT = vbuf + SZ;         // 8,388,608 bf16, dead after k_qkv
  // union region overlaid on imgT:
  float* ctxp = (float*)imgT;     // 4*262144 f32
  float* ctx = ctxp + 4 * 262144; // (unused f32 slot, kept for layout stability)
  float* ps = ctx + 262144;       // 32768
  float* ps2 = ps + 32768;        // 32768
  float* mu = ps2 + 32768;        // 64
  float* rs = mu + 64;            // 64
  bf16* wb = imgT + 8388608;      // 393,216 bf16
  bf16* sxbuf = wb + 393216;      // SZ: sxT -> dead -> contentT [b][m][512]
  bf16* wb2 = sxbuf + SZ;         // 131,072 bf16 (w_out)
  bf16* relcb = wb2 + 131072;     // 8,192 bf16
  bf16* relrb = relcb + 8192;     // 8,192 bf16
  bf16* ctxTb = relrb + 8192;     // 262,144 bf16 (ctx^T)
  // total ~152.5 MB

  k_cvt_all<<<2112, 256, 0, stream>>>(w_qkv, w_out, rel_cols, rel_rows, wb, wb2, relcb, relrb);
  k_timg<<<dim3(64, 4, 8), 256, 0, stream>>>(img, imgT);
  k_qkv<<<dim3(32, 12, 8), 256, 0, stream>>>(wb, imgT, qbuf, kbuf, vbuf);
  k_softmax<<<4096, 256, 0, stream>>>(kbuf);
  k_ctx2<<<dim3(4, 64), 256, 0, stream>>>(kbuf, vbuf, ctxp);
  k_ctxred_T<<<64, 256, 0, stream>>>(ctxp, ctxTb);
  // rel-row path
  k_sx2<<<dim3(64, 64), 256, 0, stream>>>(relrb, qbuf, sxbuf);       // sxT
  k_vt<<<dim3(8, 64), 256, 0, stream>>>(vbuf, kbuf);                 // kbuf := vT (k dead)
  k_yh2<<<dim3(64, 64), 256, 0, stream>>>(kbuf, sxbuf, vbuf);        // vbuf := yhT (v dead)
  k_bnpart2<<<dim3(8, 64), 256, 0, stream>>>(vbuf, ps, ps2);
  k_bnfin<<<1, 64, 0, stream>>>(ps, ps2, mu, rs);
  // fused content + rel-col into contentT = sxbuf (sxT dead)
  k_crc<<<dim3(64, 64), 256, 0, stream>>>(ctxTb, qbuf, vbuf, relcb, mu, rs, gamma, beta, sxbuf);
  k_final<<<dim3(32, 2, 8), 256, 0, stream>>>(wb2, sxbuf, b_out, out);
}

// Round 17
// 198.175 us; speedup vs baseline: 1.0324x; 1.0052x over previous
//
#include <hip/hip_runtime.h>
#include <hip/hip_bf16.h>
#include <math.h>

// Problem constants
#define NH   64     // b*H heads
#define DKC  64     // dim per head
#define MM   4096   // x*y
#define CC   256    // img channels
#define RRN  127    // 2L-1

typedef __hip_bfloat16 bf16;
__device__ __forceinline__ float b2f(bf16 x) { return __bfloat162float(x); }
__device__ __forceinline__ bf16 f2b(float x) { return __float2bfloat16(x); }
__device__ __forceinline__ unsigned short bbits(float x) { bf16 h = f2b(x); return *(unsigned short*)&h; }
__device__ __forceinline__ float fbits(unsigned short u) { bf16 h = *(bf16*)&u; return b2f(h); }

typedef short bf16x8 __attribute__((ext_vector_type(8)));
typedef float f32x4 __attribute__((ext_vector_type(4)));
typedef unsigned short u16;
typedef u16 u16x4 __attribute__((ext_vector_type(4)));
typedef u16 u16x8 __attribute__((ext_vector_type(8)));

#define AS1 __attribute__((address_space(1)))
#define AS3 __attribute__((address_space(3)))
#define GLOAD16(gp, lp) __builtin_amdgcn_global_load_lds((const AS1 void*)(gp), (AS3 void*)(lp), 16, 0, 0)

// swizzled source elem offset for staging (involution partner of FRSWZ)
__device__ __forceinline__ int swzsrc(int lane) { return 8 * ((lane & 7) ^ (lane >> 3)); }
// fragment-read elem index within a 64-elem row, row-swizzled
#define FRSWZ(kelem, row) ((kelem) ^ (((row) & 7) * 8))

// ---------------------------------------------------------------------------
// K0a: merged converts. grid 2112 x 256 covers 540672 slots.
// ---------------------------------------------------------------------------
__global__ __launch_bounds__(256) void k_cvt_all(const float* __restrict__ w_qkv, const float* __restrict__ w_out,
                                                 const float* __restrict__ relc, const float* __restrict__ relr,
                                                 bf16* __restrict__ wb, bf16* __restrict__ wb2,
                                                 bf16* __restrict__ relcb, bf16* __restrict__ relrb) {
  const int i = blockIdx.x * 256 + threadIdx.x;
  if (i < 393216) {
    wb[i] = f2b(w_qkv[i]);
  } else if (i < 524288) {
    int j = i - 393216; wb2[j] = f2b(w_out[j]);
  } else if (i < 532480) {
    int j = i - 524288; relcb[j] = (j < RRN * 64) ? f2b(relc[j]) : f2b(0.f);
  } else {
    int j = i - 532480; if (j < RRN * 64) relrb[j] = f2b(relr[j]);
  }
}

// ---------------------------------------------------------------------------
// K0b: img fp32 [8][256][4096] -> bf16 imgT [8][4096][256], vectorized
// ---------------------------------------------------------------------------
__global__ __launch_bounds__(256) void k_timg(const float* __restrict__ img, bf16* __restrict__ imgT) {
  const int b = blockIdx.z, c0 = blockIdx.y * 64, m0 = blockIdx.x * 64;
  const int tid = threadIdx.x;
  __shared__ short T[64 * 66];
  const float* ib = img + ((size_t)b * CC + c0) * MM + m0;
#pragma unroll
  for (int j = 0; j < 4; ++j) {
    int f4 = j * 256 + tid;          // 0..1023
    int cc = f4 >> 4, mm4 = (f4 & 15) * 4;
    f32x4 v = *(const f32x4*)&ib[(size_t)cc * MM + mm4];
#pragma unroll
    for (int k = 0; k < 4; ++k) T[cc * 66 + mm4 + k] = (short)bbits(v[k]);
  }
  __syncthreads();
  bf16* ob = imgT + ((size_t)b * MM + m0) * CC + c0;
#pragma unroll
  for (int j = 0; j < 4; ++j) {
    int f4 = j * 256 + tid;
    int mm = f4 >> 4, cc4 = (f4 & 15) * 4;
    u16x4 pk;
#pragma unroll
    for (int k = 0; k < 4; ++k) pk[k] = (u16)T[(cc4 + k) * 66 + mm];
    *(u16x4*)&ob[(size_t)mm * CC + cc4] = pk;
  }
}

// ---------------------------------------------------------------------------
// K1: MFMA qkv GEMM (128x128 tile, BK=64, 4 waves), A+B LDS-staged, swizzled.
// ---------------------------------------------------------------------------
__global__ __launch_bounds__(256) void k_qkv(const bf16* __restrict__ wb, const bf16* __restrict__ imgT,
                                             bf16* __restrict__ qT, bf16* __restrict__ kk, bf16* __restrict__ v) {
  const int bI = blockIdx.z;
  const int o0 = blockIdx.y * 128;
  const int m0 = blockIdx.x * 128;
  const int tid = threadIdx.x;
  const int lane = tid & 63, wid = tid >> 6;
  const int fr = lane & 15;
  const int fq = lane >> 4;
  const int wm = (wid >> 1) * 64, wn = (wid & 1) * 64;

  __shared__ __align__(16) short smem[17408];  // As[8192] | Bs[8192]; epilogue: Cs[128][136]
  short* As = smem;
  short* Bs = smem + 8192;

  const bf16* iB = imgT + (size_t)bI * MM * CC;

  f32x4 acc[4][4];
#pragma unroll
  for (int mi = 0; mi < 4; ++mi)
#pragma unroll
    for (int ni = 0; ni < 4; ++ni) acc[mi][ni] = (f32x4){0.f, 0.f, 0.f, 0.f};

  const int srow = lane >> 3;
  const int skc = swzsrc(lane);

  for (int kt = 0; kt < 4; ++kt) {
    const int k0 = kt * 64;
#pragma unroll
    for (int cc = 0; cc < 4; ++cc) {
      const int c = wid * 4 + cc;
      const int r = c * 8 + srow;
      GLOAD16(wb + (size_t)(o0 + r) * CC + k0 + skc, &As[c * 512]);
      GLOAD16(iB + (size_t)(m0 + r) * CC + k0 + skc, &Bs[c * 512]);
    }
    __syncthreads();
    bf16x8 af[4][2], bfr[4][2];
#pragma unroll
    for (int mi = 0; mi < 4; ++mi)
#pragma unroll
      for (int kkk = 0; kkk < 2; ++kkk)
        af[mi][kkk] = *(const bf16x8*)&As[(wm + mi * 16 + fr) * 64 + FRSWZ(kkk * 32 + fq * 8, fr)];
#pragma unroll
    for (int ni = 0; ni < 4; ++ni)
#pragma unroll
      for (int kkk = 0; kkk < 2; ++kkk)
        bfr[ni][kkk] = *(const bf16x8*)&Bs[(wn + ni * 16 + fr) * 64 + FRSWZ(kkk * 32 + fq * 8, fr)];
#pragma unroll
    for (int mi = 0; mi < 4; ++mi)
#pragma unroll
      for (int ni = 0; ni < 4; ++ni)
#pragma unroll
        for (int kkk = 0; kkk < 2; ++kkk)
          acc[mi][ni] = __builtin_amdgcn_mfma_f32_16x16x32_bf16(af[mi][kkk], bfr[ni][kkk], acc[mi][ni], 0, 0, 0);
    __syncthreads();
  }

  short* Cs = smem;  // pitch 136 (16B-aligned rows, bank-shifted)
  if (o0 < 512) {
    // q path: store transposed Cs[m][o] so d is contiguous on output
#pragma unroll
    for (int mi = 0; mi < 4; ++mi)
#pragma unroll
      for (int ni = 0; ni < 4; ++ni)
#pragma unroll
        for (int r = 0; r < 4; ++r)
          Cs[(wn + ni * 16 + fr) * 136 + wm + mi * 16 + fq * 4 + r] = (short)bbits(acc[mi][ni][r]);
    __syncthreads();
    const int n0 = bI * 8 + (o0 >> 6);
#pragma unroll
    for (int j = 0; j < 8; ++j) {
      int flat = tid + j * 256;
      int m = flat >> 4, nh = (flat >> 3) & 1, ds = flat & 7;
      u16x8 pk = *(const u16x8*)&Cs[m * 136 + nh * 64 + ds * 8];
      *(u16x8*)&qT[((size_t)(n0 + nh) * MM + m0 + m) * 64 + ds * 8] = pk;
    }
  } else {
    // k/v path: Cs[o][m], rows contiguous on output
#pragma unroll
    for (int mi = 0; mi < 4; ++mi)
#pragma unroll
      for (int ni = 0; ni < 4; ++ni)
#pragma unroll
        for (int r = 0; r < 4; ++r)
          Cs[(wm + mi * 16 + fq * 4 + r) * 136 + wn + ni * 16 + fr] = (short)bbits(acc[mi][ni][r]);
    __syncthreads();
    bf16* dst = (o0 < 1024) ? kk : v;
    const int obase = (o0 < 1024) ? (o0 - 512) : (o0 - 1024);
#pragma unroll
    for (int j = 0; j < 8; ++j) {
      int flat = tid + j * 256;
      int row = flat >> 4, seg = flat & 15;
      u16x8 pk = *(const u16x8*)&Cs[row * 136 + seg * 8];
      *(u16x8*)&dst[((size_t)bI * 512 + obase + row) * MM + m0 + seg * 8] = pk;
    }
  }
}

// ---------------------------------------------------------------------------
// K2: in-place softmax, row cached in registers: 1 read + 1 write
// ---------------------------------------------------------------------------
__global__ __launch_bounds__(256) void k_softmax(bf16* __restrict__ kk) {
  const size_t row = blockIdx.x;
  bf16* p = kk + row * (size_t)MM;
  const int t = threadIdx.x;
  __shared__ float sred[4];
  float v[16];
  float mx = -1e30f;
#pragma unroll
  for (int j = 0; j < 4; ++j) {
    u16x4 v4 = *(const u16x4*)&p[(j * 256 + t) * 4];
#pragma unroll
    for (int k = 0; k < 4; ++k) { v[j * 4 + k] = fbits(v4[k]); mx = fmaxf(mx, v[j * 4 + k]); }
  }
#pragma unroll
  for (int off = 32; off; off >>= 1) mx = fmaxf(mx, __shfl_down(mx, off));
  if ((t & 63) == 0) sred[t >> 6] = mx;
  __syncthreads();
  mx = fmaxf(fmaxf(sred[0], sred[1]), fmaxf(sred[2], sred[3]));
  __syncthreads();
  float s = 0.f;
#pragma unroll
  for (int i = 0; i < 16; ++i) { v[i] = expf(v[i] - mx); s += v[i]; }
#pragma unroll
  for (int off = 32; off; off >>= 1) s += __shfl_down(s, off);
  if ((t & 63) == 0) sred[t >> 6] = s;
  __syncthreads();
  s = sred[0] + sred[1] + sred[2] + sred[3];
  const float inv = 1.0f / s;
#pragma unroll
  for (int j = 0; j < 4; ++j) {
    u16x4 o;
#pragma unroll
    for (int k = 0; k < 4; ++k) o[k] = bbits(v[j * 4 + k] * inv);
    *(u16x4*)&p[(j * 256 + t) * 4] = o;
  }
}

// ---------------------------------------------------------------------------
// K3a: MFMA ctx: part[ch][n][d][e] = sum_{m in chunk} k[n,d,m]*v[n,e,m]
// 8 chunks x 64 n = 512 blocks (2 blocks/CU), 8 K-iters each.
// ---------------------------------------------------------------------------
__global__ __launch_bounds__(256) void k_ctx2(const bf16* __restrict__ kk, const bf16* __restrict__ v,
                                              float* __restrict__ part) {
  const int ch = blockIdx.x, n = blockIdx.y;
  const int tid = threadIdx.x;
  const int lane = tid & 63, wid = tid >> 6;
  const int fr = lane & 15, fq = lane >> 4;
  const int wr = (wid >> 1) * 32, wc = (wid & 1) * 32;
  __shared__ __align__(16) short Ks[64 * 64];
  __shared__ __align__(16) short Vs[64 * 64];
  const bf16* kp = kk + (size_t)n * DKC * MM;
  const bf16* vp = v + (size_t)n * DKC * MM;
  const int srow = lane >> 3;
  const int skc = swzsrc(lane);

  f32x4 acc[2][2];
#pragma unroll
  for (int mi = 0; mi < 2; ++mi)
#pragma unroll
    for (int ni = 0; ni < 2; ++ni) acc[mi][ni] = (f32x4){0.f, 0.f, 0.f, 0.f};

  for (int t = 0; t < 8; ++t) {
    const int m0 = ch * 512 + t * 64;
#pragma unroll
    for (int cc = 0; cc < 4; ++cc) {
      const int c = wid * 4 + cc;
      if (c < 8) {
        const int r = c * 8 + srow;
        GLOAD16(kp + (size_t)r * MM + m0 + skc, &Ks[c * 512]);
      } else {
        const int r = (c - 8) * 8 + srow;
        GLOAD16(vp + (size_t)r * MM + m0 + skc, &Vs[(c - 8) * 512]);
      }
    }
    __syncthreads();
    bf16x8 af[2][2], bf[2][2];
#pragma unroll
    for (int mi = 0; mi < 2; ++mi)
#pragma unroll
      for (int kkx = 0; kkx < 2; ++kkx)
        af[mi][kkx] = *(const bf16x8*)&Ks[(wr + mi * 16 + fr) * 64 + FRSWZ(kkx * 32 + fq * 8, fr)];
#pragma unroll
    for (int ni = 0; ni < 2; ++ni)
#pragma unroll
      for (int kkx = 0; kkx < 2; ++kkx)
        bf[ni][kkx] = *(const bf16x8*)&Vs[(wc + ni * 16 + fr) * 64 + FRSWZ(kkx * 32 + fq * 8, fr)];
#pragma unroll
    for (int mi = 0; mi < 2; ++mi)
#pragma unroll
      for (int ni = 0; ni < 2; ++ni)
#pragma unroll
        for (int kkx = 0; kkx < 2; ++kkx)
          acc[mi][ni] = __builtin_amdgcn_mfma_f32_16x16x32_bf16(af[mi][kkx], bf[ni][kkx], acc[mi][ni], 0, 0, 0);
    __syncthreads();
  }
  float* pb = part + ((size_t)ch * NH + n) * 4096;
#pragma unroll
  for (int mi = 0; mi < 2; ++mi)
#pragma unroll
    for (int ni = 0; ni < 2; ++ni)
#pragma unroll
      for (int r = 0; r < 4; ++r)
        pb[(wr + mi * 16 + fq * 4 + r) * 64 + wc + ni * 16 + fr] = acc[mi][ni][r];
}

// K3b: reduce 8 partials + transpose + convert: part -> ctxTb[n][e][d] bf16
__global__ __launch_bounds__(256) void k_ctxred_T(const float* __restrict__ part, bf16* __restrict__ ctxTb) {
  const int n = blockIdx.x;
  const int tid = threadIdx.x;
  __shared__ float T[64 * 67];  // T[d][e]
  const float* pn = part + (size_t)n * 4096;
#pragma unroll
  for (int l = 0; l < 16; ++l) {
    int idx = tid + l * 256;
    int d = idx >> 6, e = idx & 63;
    float s = 0.f;
#pragma unroll
    for (int c = 0; c < 8; ++c) s += pn[(size_t)c * 262144 + idx];
    T[d * 67 + e] = s;
  }
  __syncthreads();
  bf16* ob = ctxTb + (size_t)n * 4096;
#pragma unroll
  for (int l = 0; l < 4; ++l) {
    int q = tid + l * 256;
    int e = q >> 4, d4 = (q & 15) * 4;
    u16x4 pk;
#pragma unroll
    for (int k = 0; k < 4; ++k) pk[k] = bbits(T[(d4 + k) * 67 + e]);
    *(u16x4*)&ob[e * 64 + d4] = pk;
  }
}

// ---------------------------------------------------------------------------
// K5a: MFMA k_sx2: sxT[n][y][x][i] = sum_d relr[i+63-x][d]*qT[n][x*64+y][d]
// ---------------------------------------------------------------------------
__global__ __launch_bounds__(256) void k_sx2(const bf16* __restrict__ relrb, const bf16* __restrict__ qT,
                                             bf16* __restrict__ sxT) {
  const int x = blockIdx.x, n = blockIdx.y;
  const int tid = threadIdx.x;
  const int lane = tid & 63, wid = tid >> 6;
  const int fr = lane & 15, fq = lane >> 4;
  const int wr = (wid >> 1) * 32, wc = (wid & 1) * 32;  // wr: i, wc: y
  __shared__ __align__(16) short Qt[64 * 64];   // Qt[y][d], swizzled
  const bf16* qrow = qT + ((size_t)n * MM + x * 64) * 64;
  const int srow = lane >> 3, skc = swzsrc(lane);
#pragma unroll
  for (int cc = 0; cc < 2; ++cc) {
    const int c = wid * 2 + cc;          // 0..7
    const int r = c * 8 + srow;          // y row
    GLOAD16(qrow + (size_t)r * 64 + skc, &Qt[c * 512]);
  }
  bf16x8 af[2][2];
#pragma unroll
  for (int mi = 0; mi < 2; ++mi) {
    const int j = wr + mi * 16 + fr + 63 - x;
#pragma unroll
    for (int kk = 0; kk < 2; ++kk)
      af[mi][kk] = *(const bf16x8*)&relrb[(size_t)j * 64 + kk * 32 + fq * 8];
  }
  __syncthreads();
  bf16x8 bq[2][2];
#pragma unroll
  for (int ni = 0; ni < 2; ++ni) {
    const int row = wc + ni * 16 + fr;
#pragma unroll
    for (int kk = 0; kk < 2; ++kk)
      bq[ni][kk] = *(const bf16x8*)&Qt[row * 64 + FRSWZ(kk * 32 + fq * 8, fr)];
  }
  f32x4 acc[2][2];
#pragma unroll
  for (int mi = 0; mi < 2; ++mi)
#pragma unroll
    for (int ni = 0; ni < 2; ++ni) acc[mi][ni] = (f32x4){0.f, 0.f, 0.f, 0.f};
#pragma unroll
  for (int mi = 0; mi < 2; ++mi)
#pragma unroll
    for (int ni = 0; ni < 2; ++ni)
#pragma unroll
      for (int kk = 0; kk < 2; ++kk)
        acc[mi][ni] = __builtin_amdgcn_mfma_f32_16x16x32_bf16(af[mi][kk], bq[ni][kk], acc[mi][ni], 0, 0, 0);
  // D[row=i][col=y] -> sxT[n][y][x][i], 4 consecutive i per store
#pragma unroll
  for (int mi = 0; mi < 2; ++mi)
#pragma unroll
    for (int ni = 0; ni < 2; ++ni) {
      const int yy2 = wc + ni * 16 + fr;
      u16x4 pk;
#pragma unroll
      for (int r = 0; r < 4; ++r) pk[r] = bbits(acc[mi][ni][r]);
      *(u16x4*)&sxT[(((size_t)n * 64 + yy2) * 64 + x) * 64 + wr + mi * 16 + fq * 4] = pk;
    }
}

// ---------------------------------------------------------------------------
// K5v: k_vt — transpose v[n][e][x][y] -> vT[n][y][e][x]
// ---------------------------------------------------------------------------
__global__ __launch_bounds__(256) void k_vt(const bf16* __restrict__ v, bf16* __restrict__ vT) {
  const int eg = blockIdx.x, n = blockIdx.y;
  const int tid = threadIdx.x;
  __shared__ short T[8 * 64 * 66];  // T[e][y][x], pitch 66
  const bf16* vp = v + (size_t)n * DKC * MM + (size_t)eg * 8 * MM;
#pragma unroll
  for (int j = 0; j < 16; ++j) {
    int flat = (j * 256 + tid) * 8;
    int e = flat >> 12, m = flat & 4095;
    int x = m >> 6, y0 = m & 63;
    u16x4 lo = *(const u16x4*)&vp[(size_t)e * MM + m];
    u16x4 hi = *(const u16x4*)&vp[(size_t)e * MM + m + 4];
#pragma unroll
    for (int k = 0; k < 4; ++k) T[(e * 64 + y0 + k) * 66 + x] = (short)lo[k];
#pragma unroll
    for (int k = 0; k < 4; ++k) T[(e * 64 + y0 + 4 + k) * 66 + x] = (short)hi[k];
  }
  __syncthreads();
#pragma unroll
  for (int j = 0; j < 32; ++j) {
    int flat4 = j * 256 + tid;            // 8192 quads
    int x4 = flat4 & 15, e = (flat4 >> 4) & 7, y = flat4 >> 7;
    u16x4 pk;
#pragma unroll
    for (int r = 0; r < 4; ++r) pk[r] = (u16)T[(e * 64 + y) * 66 + x4 * 4 + r];
    *(u16x4*)&vT[(((size_t)n * 64 + y) * 64 + eg * 8 + e) * 64 + x4 * 4] = pk;
  }
}

// ---------------------------------------------------------------------------
// K5b: k_yh2 — MFMA per (n,y): yhT[n][y][x][e] = sum_i vT[n][y][e][i]*sxT[n][y][x][i]
// ---------------------------------------------------------------------------
__global__ __launch_bounds__(256) void k_yh2(const bf16* __restrict__ vT, const bf16* __restrict__ sxT,
                                             bf16* __restrict__ yhT) {
  const int y = blockIdx.x, n = blockIdx.y;
  const int tid = threadIdx.x;
  const int lane = tid & 63, wid = tid >> 6;
  const int fr = lane & 15, fq = lane >> 4;
  const int wr = (wid >> 1) * 32, wc = (wid & 1) * 32;  // wr: e, wc: x
  __shared__ __align__(16) short Va[64 * 64];
  __shared__ __align__(16) short Sa[64 * 64];
  const size_t rb = ((size_t)n * 64 + y) * 4096;
  const int srow = lane >> 3;
  const int skc = swzsrc(lane);
#pragma unroll
  for (int cc = 0; cc < 2; ++cc) {
    const int c = wid * 2 + cc;
    const int r = c * 8 + srow;
    GLOAD16(vT + rb + (size_t)r * 64 + skc, &Va[c * 512]);
    GLOAD16(sxT + rb + (size_t)r * 64 + skc, &Sa[c * 512]);
  }
  __syncthreads();
  bf16x8 av[2][2], bs[2][2];
#pragma unroll
  for (int mi = 0; mi < 2; ++mi)
#pragma unroll
    for (int kk = 0; kk < 2; ++kk)
      av[mi][kk] = *(const bf16x8*)&Va[(wr + mi * 16 + fr) * 64 + FRSWZ(kk * 32 + fq * 8, fr)];
#pragma unroll
  for (int ni = 0; ni < 2; ++ni)
#pragma unroll
    for (int kk = 0; kk < 2; ++kk)
      bs[ni][kk] = *(const bf16x8*)&Sa[(wc + ni * 16 + fr) * 64 + FRSWZ(kk * 32 + fq * 8, fr)];
  f32x4 acc[2][2];
#pragma unroll
  for (int mi = 0; mi < 2; ++mi)
#pragma unroll
    for (int ni = 0; ni < 2; ++ni) acc[mi][ni] = (f32x4){0.f, 0.f, 0.f, 0.f};
#pragma unroll
  for (int mi = 0; mi < 2; ++mi)
#pragma unroll
    for (int ni = 0; ni < 2; ++ni)
#pragma unroll
      for (int kk = 0; kk < 2; ++kk)
        acc[mi][ni] = __builtin_amdgcn_mfma_f32_16x16x32_bf16(av[mi][kk], bs[ni][kk], acc[mi][ni], 0, 0, 0);
#pragma unroll
  for (int mi = 0; mi < 2; ++mi)
#pragma unroll
    for (int ni = 0; ni < 2; ++ni) {
      const int xo = wc + ni * 16 + fr;
      u16x4 pk;
#pragma unroll
      for (int r = 0; r < 4; ++r) pk[r] = bbits(acc[mi][ni][r]);
      *(u16x4*)&yhT[rb + (size_t)xo * 64 + wr + mi * 16 + fq * 4] = pk;
    }
}

// ---------------------------------------------------------------------------
// K6a: BN partial stats from yhT. grid (8 row-groups, 64 n)
// ---------------------------------------------------------------------------
__global__ __launch_bounds__(256) void k_bnpart2(const bf16* __restrict__ yhT, float* __restrict__ ps,
                                                 float* __restrict__ ps2) {
  const int gg = blockIdx.x, n = blockIdx.y;
  const int t = threadIdx.x;
  const int eq = (t & 15) * 4, rg = t >> 4;
  const bf16* p = yhT + (size_t)n * 262144 + (size_t)gg * 512 * 64;
  float s[4] = {}, s2[4] = {};
  for (int r = rg; r < 512; r += 16) {
    u16x4 v4 = *(const u16x4*)&p[(size_t)r * 64 + eq];
#pragma unroll
    for (int k = 0; k < 4; ++k) { float x = fbits(v4[k]); s[k] += x; s2[k] += x * x; }
  }
  __shared__ float ls[16][64], ls2[16][64];
#pragma unroll
  for (int k = 0; k < 4; ++k) { ls[rg][eq + k] = s[k]; ls2[rg][eq + k] = s2[k]; }
  __syncthreads();
  if (t < 64) {
    float S = 0.f, S2 = 0.f;
#pragma unroll
    for (int g = 0; g < 16; ++g) { S += ls[g][t]; S2 += ls2[g][t]; }
    ps[t * 512 + n * 8 + gg] = S;
    ps2[t * 512 + n * 8 + gg] = S2;
  }
}

// K6b: finalize BN stats
__global__ __launch_bounds__(64) void k_bnfin(const float* __restrict__ ps, const float* __restrict__ ps2,
                                              float* __restrict__ mu, float* __restrict__ rs) {
  const int e = threadIdx.x;
  float S = 0.f, S2 = 0.f;
  for (int g = 0; g < 512; ++g) { S += ps[e * 512 + g]; S2 += ps2[e * 512 + g]; }
  const float invN = 1.0f / (NH * (float)MM);
  float m = S * invN;
  float var = S2 * invN - m * m;
  mu[e] = m;
  rs[e] = 1.0f / sqrtf(var + 1e-5f);
}

// ---------------------------------------------------------------------------
// K7: k_crc — fused content + rel-col per (n,x), single fresh write.
// ---------------------------------------------------------------------------
__global__ __launch_bounds__(256) void k_crc(const bf16* __restrict__ ctxTb, const bf16* __restrict__ qT,
                                             const bf16* __restrict__ yhT, const bf16* __restrict__ relcb,
                                             const float* __restrict__ mu, const float* __restrict__ rs,
                                             const float* __restrict__ gamma, const float* __restrict__ beta,
                                             bf16* __restrict__ contentT) {
  const int xx = blockIdx.x, n = blockIdx.y;
  const int bI = n >> 3, h = n & 7;
  const int tid = threadIdx.x;
  const int lane = tid & 63, wv = tid >> 6;
  const int fr = lane & 15, fq = lane >> 4;
  __shared__ __align__(16) short smem[4096 + 8448 + 4608];
  short* Qt = smem;                         // [64][64] linear, swizzled (via GLOAD16)
  bf16* Scb = (bf16*)(smem + 4096);         // [128][66] j-major, scalar-only
  bf16* Ysb = (bf16*)(smem + 4096 + 8448);  // [64][72] e-major, i XOR-swizzled
  short* DT = smem;                         // overlay on Qt after stage 1: [64][64] FRSWZ

  const size_t nb = (size_t)n * DKC * MM;

  // stage Qt via global_load_lds (rows y, 64 d each; pre-swizzled source)
  {
    const bf16* qrow = qT + ((size_t)n * MM + xx * 64) * 64;
    const int srow = lane >> 3, skc = swzsrc(lane);
#pragma unroll
    for (int cc = 0; cc < 2; ++cc) {
      const int c = wv * 2 + cc;
      const int r = c * 8 + srow;
      GLOAD16(qrow + (size_t)r * 64 + skc, &Qt[c * 512]);
    }
  }
  // Ysb = BN(yh) from yhT[n][i][xx][e] — e-contiguous reads, swizzled transpose store
#pragma unroll
  for (int l = 0; l < 16; ++l) {
    int idx = tid + l * 256;
    int i = idx >> 6, e = idx & 63;
    float val = (b2f(yhT[nb + (size_t)i * 4096 + xx * 64 + e]) - mu[e]) * rs[e] * gamma[e] + beta[e];
    Ysb[e * 72 + (i ^ (8 * (e >> 3)))] = f2b(val);
  }
  // A-fragments: relcb (stage 1) and ctxTb (content), direct from global
  bf16x8 afr[2][2], aCT[2];
#pragma unroll
  for (int mi = 0; mi < 2; ++mi)
#pragma unroll
    for (int kk = 0; kk < 2; ++kk)
      afr[mi][kk] = *(const bf16x8*)&relcb[(size_t)(wv * 32 + mi * 16 + fr) * 64 + kk * 32 + fq * 8];
#pragma unroll
  for (int kk = 0; kk < 2; ++kk)
    aCT[kk] = *(const bf16x8*)&ctxTb[(size_t)n * 4096 + (wv * 16 + fr) * 64 + kk * 32 + fq * 8];
  __syncthreads();

  // stage 1 MFMA: Sc[j][y], wave wv owns j in [wv*32, wv*32+32)
  f32x4 acc1[2][4];
#pragma unroll
  for (int mi = 0; mi < 2; ++mi)
#pragma unroll
    for (int ni = 0; ni < 4; ++ni) acc1[mi][ni] = (f32x4){0.f, 0.f, 0.f, 0.f};
  bf16x8 bq[4][2];
#pragma unroll
  for (int ni = 0; ni < 4; ++ni) {
    const int row = ni * 16 + fr;
#pragma unroll
    for (int kk = 0; kk < 2; ++kk)
      bq[ni][kk] = *(const bf16x8*)&Qt[row * 64 + FRSWZ(kk * 32 + fq * 8, fr)];
  }
#pragma unroll
  for (int mi = 0; mi < 2; ++mi)
#pragma unroll
    for (int ni = 0; ni < 4; ++ni)
#pragma unroll
      for (int kk = 0; kk < 2; ++kk)
        acc1[mi][ni] = __builtin_amdgcn_mfma_f32_16x16x32_bf16(afr[mi][kk], bq[ni][kk], acc1[mi][ni], 0, 0, 0);
#pragma unroll
  for (int mi = 0; mi < 2; ++mi)
#pragma unroll
    for (int ni = 0; ni < 4; ++ni)
#pragma unroll
      for (int r = 0; r < 4; ++r)
        Scb[(wv * 32 + mi * 16 + fq * 4 + r) * 66 + ni * 16 + fr] = f2b(acc1[mi][ni][r]);
  __syncthreads();

  // DT[y][i] = Sc[i-y+63][y], stored FRSWZ-swizzled (overlay on Qt; bq in regs)
#pragma unroll
  for (int l = 0; l < 16; ++l) {
    int idx = tid + l * 256;
    int y = idx >> 6, i = idx & 63;
    DT[y * 64 + FRSWZ(i, y)] = *(const short*)&Scb[(i - y + 63) * 66 + y];
  }
  __syncthreads();

  // acc2 = content (aCT x bq) + relcol (a2 x bd), wave wv owns e in [wv*16,+16)
  f32x4 acc2[4];
#pragma unroll
  for (int ni = 0; ni < 4; ++ni) acc2[ni] = (f32x4){0.f, 0.f, 0.f, 0.f};
#pragma unroll
  for (int ni = 0; ni < 4; ++ni)
#pragma unroll
    for (int kk = 0; kk < 2; ++kk)
      acc2[ni] = __builtin_amdgcn_mfma_f32_16x16x32_bf16(aCT[kk], bq[ni][kk], acc2[ni], 0, 0, 0);
  bf16x8 a2[2], bd[4][2];
  {
    const int row = wv * 16 + fr;
    const int swz = 8 * (row >> 3);
#pragma unroll
    for (int kk = 0; kk < 2; ++kk)
      a2[kk] = *(const bf16x8*)&Ysb[row * 72 + ((kk * 32 + fq * 8) ^ swz)];
  }
#pragma unroll
  for (int ni = 0; ni < 4; ++ni) {
    const int row = ni * 16 + fr;
#pragma unroll
    for (int kk = 0; kk < 2; ++kk)
      bd[ni][kk] = *(const bf16x8*)&DT[row * 64 + FRSWZ(kk * 32 + fq * 8, fr)];
  }
#pragma unroll
  for (int ni = 0; ni < 4; ++ni)
#pragma unroll
    for (int kk = 0; kk < 2; ++kk)
      acc2[ni] = __builtin_amdgcn_mfma_f32_16x16x32_bf16(a2[kk], bd[ni][kk], acc2[ni], 0, 0, 0);

  // single fresh write to contentT[b][m][512]
  bf16* cb = contentT + (size_t)bI * MM * 512;
#pragma unroll
  for (int ni = 0; ni < 4; ++ni) {
    size_t a = (size_t)(xx * 64 + ni * 16 + fr) * 512 + h * 64 + wv * 16 + fq * 4;
    u16x4 pk;
#pragma unroll
    for (int r = 0; r < 4; ++r) pk[r] = bbits(acc2[ni][r]);
    *(u16x4*)&cb[a] = pk;
  }
}

// ---------------------------------------------------------------------------
// K8: MFMA final GEMM, A+B LDS-staged, swizzled. Epilogue: LDS reassembly,
// two 64-row halves, coalesced f32x4 stores with bias.
// ---------------------------------------------------------------------------
__global__ __launch_bounds__(256) void k_final(const bf16* __restrict__ wb2, const bf16* __restrict__ cT,
                                               const float* __restrict__ bout, float* __restrict__ dout) {
  const int bI = blockIdx.z;
  const int o0 = blockIdx.y * 128;
  const int m0 = blockIdx.x * 128;
  const int tid = threadIdx.x;
  const int lane = tid & 63, wid = tid >> 6;
  const int fr = lane & 15;
  const int fq = lane >> 4;
  const int wm = (wid >> 1) * 64, wn = (wid & 1) * 64;

  __shared__ __align__(16) short smem[17408];  // As|Bs; epilogue: Cf[64][132] f32
  short* As = smem;
  short* Bs = smem + 8192;

  const bf16* cB = cT + (size_t)bI * MM * 512;

  f32x4 acc[4][4];
#pragma unroll
  for (int mi = 0; mi < 4; ++mi)
#pragma unroll
    for (int ni = 0; ni < 4; ++ni) acc[mi][ni] = (f32x4){0.f, 0.f, 0.f, 0.f};

  const int srow = lane >> 3;
  const int skc = swzsrc(lane);

  for (int kt = 0; kt < 8; ++kt) {
    const int k0 = kt * 64;
#pragma unroll
    for (int cc = 0; cc < 4; ++cc) {
      const int c = wid * 4 + cc;
      const int r = c * 8 + srow;
      GLOAD16(wb2 + (size_t)(o0 + r) * 512 + k0 + skc, &As[c * 512]);
      GLOAD16(cB + (size_t)(m0 + r) * 512 + k0 + skc, &Bs[c * 512]);
    }
    __syncthreads();
    bf16x8 af[4][2], bfr[4][2];
#pragma unroll
    for (int mi = 0; mi < 4; ++mi)
#pragma unroll
      for (int kkk = 0; kkk < 2; ++kkk)
        af[mi][kkk] = *(const bf16x8*)&As[(wm + mi * 16 + fr) * 64 + FRSWZ(kkk * 32 + fq * 8, fr)];
#pragma unroll
    for (int ni = 0; ni < 4; ++ni)
#pragma unroll
      for (int kkk = 0; kkk < 2; ++kkk)
        bfr[ni][kkk] = *(const bf16x8*)&Bs[(wn + ni * 16 + fr) * 64 + FRSWZ(kkk * 32 + fq * 8, fr)];
#pragma unroll
    for (int mi = 0; mi < 4; ++mi)
#pragma unroll
      for (int ni = 0; ni < 4; ++ni)
#pragma unroll
        for (int kkk = 0; kkk < 2; ++kkk)
          acc[mi][ni] = __builtin_amdgcn_mfma_f32_16x16x32_bf16(af[mi][kkk], bfr[ni][kkk], acc[mi][ni], 0, 0, 0);
    __syncthreads();
  }

  float* Cf = (float*)smem;  // pitch 132 floats (16B-aligned rows)
#pragma unroll
  for (int half = 0; half < 2; ++half) {
    if ((wm >> 6) == half) {
#pragma unroll
      for (int mi = 0; mi < 4; ++mi)
#pragma unroll
        for (int ni = 0; ni < 4; ++ni)
#pragma unroll
          for (int r = 0; r < 4; ++r) {
            const int rowh = mi * 16 + fq * 4 + r;
            Cf[rowh * 132 + wn + ni * 16 + fr] = acc[mi][ni][r] + bout[o0 + half * 64 + rowh];
          }
    }
    __syncthreads();
#pragma unroll
    for (int j = 0; j < 8; ++j) {
      int flat = tid + j * 256;
      int rowh = flat >> 5, seg = flat & 31;
      f32x4 pk = *(const f32x4*)&Cf[rowh * 132 + seg * 4];
      *(f32x4*)&dout[((size_t)bI * 256 + o0 + half * 64 + rowh) * MM + m0 + seg * 4] = pk;
    }
    __syncthreads();
  }
}

// ---------------------------------------------------------------------------
extern "C" void kernel_launch(void* const* d_in, const int* in_sizes, int n_in,
                              void* d_out, int out_size, void* d_ws, size_t ws_size,
                              hipStream_t stream) {
  const float* img = (const float*)d_in[0];
  const float* w_qkv = (const float*)d_in[1];
  const float* w_out = (const float*)d_in[2];
  const float* b_out = (const float*)d_in[3];
  const float* rel_rows = (const float*)d_in[4];
  const float* rel_cols = (const float*)d_in[5];
  const float* gamma = (const float*)d_in[6];
  const float* beta = (const float*)d_in[7];
  float* out = (float*)d_out;

  const size_t SZ = (size_t)NH * DKC * MM;  // 16,777,216 elements
  bf16* qbuf = (bf16*)d_ws;       // SZ bf16: qT[n][m][d]
  bf16* kbuf = qbuf + SZ;         // SZ: k -> dead -> vT
  bf16* vbuf = kbuf + SZ;         // SZ: v -> dead -> yhT [n][y][x][e]
  bf16* imgT = vbuf + SZ;         // 8,388,608 bf16, dead after k_qkv
  // union region overlaid on imgT:
  float* ctxp = (float*)imgT;     // 8*262144 f32 (8.4 MB)
  float* ps = ctxp + 8 * 262144;  // 32768
  float* ps2 = ps + 32768;        // 32768
  float* mu = ps2 + 32768;        // 64
  float* rs = mu + 64;            // 64
  bf16* wb = imgT + 8388608;      // 393,216 bf16
  bf16* sxbuf = wb + 393216;      // SZ: sxT -> dead -> contentT [b][m][512]
  bf16* wb2 = sxbuf + SZ;         // 131,072 bf16 (w_out)
  bf16* relcb = wb2 + 131072;     // 8,192 bf16
  bf16* relrb = relcb + 8192;     // 8,192 bf16
  bf16* ctxTb = relrb + 8192;     // 262,144 bf16 (ctx^T)
  // total ~152.5 MB

  k_cvt_all<<<2112, 256, 0, stream>>>(w_qkv, w_out, rel_cols, rel_rows, wb, wb2, relcb, relrb);
  k_timg<<<dim3(64, 4, 8), 256, 0, stream>>>(img, imgT);
  k_qkv<<<dim3(32, 12, 8), 256, 0, stream>>>(wb, imgT, qbuf, kbuf, vbuf);
  k_softmax<<<4096, 256, 0, stream>>>(kbuf);
  k_ctx2<<<dim3(8, 64), 256, 0, stream>>>(kbuf, vbuf, ctxp);
  k_ctxred_T<<<64, 256, 0, stream>>>(ctxp, ctxTb);
  // rel-row path
  k_sx2<<<dim3(64, 64), 256, 0, stream>>>(relrb, qbuf, sxbuf);       // sxT
  k_vt<<<dim3(8, 64), 256, 0, stream>>>(vbuf, kbuf);                 // kbuf := vT (k dead)
  k_yh2<<<dim3(64, 64), 256, 0, stream>>>(kbuf, sxbuf, vbuf);        // vbuf := yhT (v dead)
  k_bnpart2<<<dim3(8, 64), 256, 0, stream>>>(vbuf, ps, ps2);
  k_bnfin<<<1, 64, 0, stream>>>(ps, ps2, mu, rs);
  // fused content + rel-col into contentT = sxbuf (sxT dead)
  k_crc<<<dim3(64, 64), 256, 0, stream>>>(ctxTb, qbuf, vbuf, relcb, mu, rs, gamma, beta, sxbuf);
  k_final<<<dim3(32, 2, 8), 256, 0, stream>>>(wb2, sxbuf, b_out, out);
}